// Round 8
// baseline (6639.577 us; speedup 1.0000x reference)
//
#include <hip/hip_runtime.h>
#include <hip/hip_bf16.h>

#define NDS 12      // stride for num(10)+denom(1) rows / h rows
#define LS 10       // stride for xl / xr rows
#define N_CAP 200000
#define M_CAP 32768

// Static device scratch (sizes fixed by problem spec)
__device__ float    g_bufA[(size_t)N_CAP * NDS];
__device__ float    g_bufB[(size_t)N_CAP * NDS];
__device__ float    g_xl[(size_t)N_CAP * LS];
__device__ float    g_xr[(size_t)N_CAP * LS];
__device__ unsigned g_mkey[N_CAP];
__device__ float    g_p[M_CAP];
__device__ float    g_vsum[1];

__device__ __forceinline__ float* selbuf(int s) { return s ? g_bufB : g_bufA; }

// monotone float->uint key for atomicMax-based float max (0 acts as -inf)
__device__ __forceinline__ unsigned fkey(float f) {
    unsigned b = __float_as_uint(f);
    return (b & 0x80000000u) ? ~b : (b | 0x80000000u);
}
__device__ __forceinline__ float kval(unsigned k) {
    unsigned b = (k & 0x80000000u) ? (k & 0x7fffffffu) : ~k;
    return __uint_as_float(b);
}

// ---------------- init: zero p, vsum ----------------
__global__ void k_init(int M) {
    int i = blockIdx.x * blockDim.x + threadIdx.x;
    if (i < M) g_p[i] = 0.f;
    if (i == M) g_vsum[0] = 0.f;
}

// ---- per-node xl/xr from [hprev|x1]; zero accumulator rows + mkey ----
__global__ void k_gat_pre(const float* __restrict__ x1,
                          const float* __restrict__ wl, const float* __restrict__ wr,
                          int in_dim, int sel_out, int N) {
    __shared__ float swl[250], swr[250];
    for (int t = threadIdx.x; t < in_dim * 10; t += blockDim.x) { swl[t] = wl[t]; swr[t] = wr[t]; }
    __syncthreads();
    int n = blockIdx.x * blockDim.x + threadIdx.x;
    if (n >= N) return;
    const float* hprev = selbuf(1 - sel_out);
    float* acc_out = selbuf(sel_out);
    float aL[10], aR[10];
#pragma unroll
    for (int j = 0; j < 10; j++) { aL[j] = 0.f; aR[j] = 0.f; }
    int row = 0;
    if (in_dim == 25) {
        for (int k = 0; k < 10; k++) {
            float v = hprev[(size_t)n * NDS + k];
#pragma unroll
            for (int j = 0; j < 10; j++) { aL[j] += v * swl[k * 10 + j]; aR[j] += v * swr[k * 10 + j]; }
        }
        row = 10;
    }
    for (int k = 0; k < 15; k++) {
        float v = x1[(size_t)n * 15 + k];
#pragma unroll
        for (int j = 0; j < 10; j++) { aL[j] += v * swl[(row + k) * 10 + j]; aR[j] += v * swr[(row + k) * 10 + j]; }
    }
#pragma unroll
    for (int j = 0; j < 10; j++) { g_xl[(size_t)n * LS + j] = aL[j]; g_xr[(size_t)n * LS + j] = aR[j]; }
#pragma unroll
    for (int j = 0; j < NDS; j++) acc_out[(size_t)n * NDS + j] = 0.f;
    g_mkey[n] = 0u;
}

// ---------------- per-edge logit -> segment max ----------------
__global__ void k_edge_logit(const int* __restrict__ src, const int* __restrict__ dst,
                             const float* __restrict__ att, int E, int N) {
    __shared__ float satt[10];
    if (threadIdx.x < 10) satt[threadIdx.x] = att[threadIdx.x];
    __syncthreads();
    int i = blockIdx.x * blockDim.x + threadIdx.x;
    if (i >= E + N) return;
    int s, d;
    if (i < E) { s = src[i]; d = dst[i]; }
    else { s = i - E; d = s; }
    float acc = 0.f;
#pragma unroll
    for (int k = 0; k < 10; k++) {
        float t = g_xl[(size_t)s * LS + k] + g_xr[(size_t)d * LS + k];
        t = (t > 0.f) ? t : 0.2f * t;
        acc += t * satt[k];
    }
    atomicMax(&g_mkey[d], fkey(acc));
}

// -------- per-edge: recompute logit, softmax-weighted accumulate --------
__global__ void k_edge_acc(const int* __restrict__ src, const int* __restrict__ dst,
                           const float* __restrict__ att, int sel_out, int E, int N) {
    __shared__ float satt[10];
    if (threadIdx.x < 10) satt[threadIdx.x] = att[threadIdx.x];
    __syncthreads();
    int i = blockIdx.x * blockDim.x + threadIdx.x;
    if (i >= E + N) return;
    float* acc_out = selbuf(sel_out);
    int s, d;
    if (i < E) { s = src[i]; d = dst[i]; }
    else { s = i - E; d = s; }
    float acc = 0.f;
#pragma unroll
    for (int k = 0; k < 10; k++) {
        float t = g_xl[(size_t)s * LS + k] + g_xr[(size_t)d * LS + k];
        t = (t > 0.f) ? t : 0.2f * t;
        acc += t * satt[k];
    }
    unsigned kk = g_mkey[d];
    float m = (kk == 0u) ? acc : kval(kk);
    float w = __expf(fminf(acc - m, 0.f));   // acc <= m (m includes this edge)
    atomicAdd(&acc_out[(size_t)d * NDS + 10], w);
#pragma unroll
    for (int j = 0; j < 10; j++)
        atomicAdd(&acc_out[(size_t)d * NDS + j], w * g_xl[(size_t)s * LS + j]);
}

// -------- per-node normalize + bias + relu (num row -> h row, same buffer) --------
__global__ void k_gat_post(const float* __restrict__ b, int sel_out, int N) {
    __shared__ float sb[10];
    if (threadIdx.x < 10) sb[threadIdx.x] = b[threadIdx.x];
    __syncthreads();
    int n = blockIdx.x * blockDim.x + threadIdx.x;
    if (n >= N) return;
    float* buf = selbuf(sel_out);
    float den = buf[(size_t)n * NDS + 10];
    float inv = (den > 0.f) ? 1.f / den : 0.f;
#pragma unroll
    for (int j = 0; j < 10; j++) {
        float v = buf[(size_t)n * NDS + j] * inv + sb[j];
        buf[(size_t)n * NDS + j] = (v > 0.f) ? v : 0.f;
    }
}

// ---------------- attack order scoring (h = bufA) ----------------
__global__ void k_attack(const float* __restrict__ x1,
                         const int* __restrict__ asrc, const int* __restrict__ adst,
                         const float* __restrict__ aarm, const int* __restrict__ amove,
                         const float* __restrict__ aw, const float* __restrict__ ab,
                         const float* __restrict__ bw, const float* __restrict__ bb,
                         int Ma) {
    __shared__ float sw[48 * 20], sb[20], sw2[20], sb2;
    for (int t = threadIdx.x; t < 48 * 20; t += blockDim.x) sw[t] = aw[t];
    if (threadIdx.x < 20) { sb[threadIdx.x] = ab[threadIdx.x]; sw2[threadIdx.x] = bw[threadIdx.x]; }
    if (threadIdx.x == 0) sb2 = bb[0];
    __syncthreads();
    int i = blockIdx.x * blockDim.x + threadIdx.x;
    if (i >= Ma) return;
    const float* h = g_bufA;
    int s = asrc[i], d = adst[i];
    float a = aarm[i];
    float feat[48];
#pragma unroll
    for (int k = 0; k < 10; k++) feat[k] = h[(size_t)s * NDS + k];
#pragma unroll
    for (int k = 0; k < 10; k++) feat[10 + k] = h[(size_t)d * NDS + k];
#pragma unroll
    for (int k = 0; k < 12; k++) feat[20 + k] = x1[(size_t)s * 15 + 3 + k];
#pragma unroll
    for (int k = 0; k < 14; k++) feat[32 + k] = x1[(size_t)d * 15 + 1 + k];
    feat[46] = a;
    feat[47] = 0.6f * a - 0.7f * (x1[(size_t)d * 15 + 3] + x1[(size_t)d * 15 + 4]);
    float acc[20];
#pragma unroll
    for (int j = 0; j < 20; j++) acc[j] = sb[j];
#pragma unroll
    for (int k = 0; k < 48; k++) {
        float f = feat[k];
#pragma unroll
        for (int j = 0; j < 20; j++) acc[j] += f * sw[k * 20 + j];
    }
    float sres = sb2;
#pragma unroll
    for (int j = 0; j < 20; j++) { float r = (acc[j] > 0.f) ? acc[j] : 0.f; sres += r * sw2[j]; }
    atomicAdd(&g_p[amove[i]], sres);
}

// ---------------- deploy order scoring (h = bufA) ----------------
__global__ void k_deploy(const float* __restrict__ x1,
                         const int* __restrict__ dtar, const float* __restrict__ darm,
                         const int* __restrict__ dmove,
                         const float* __restrict__ cw, const float* __restrict__ cb,
                         const float* __restrict__ dw, const float* __restrict__ db,
                         int Md) {
    __shared__ float sw[23 * 20], sb[20], sw2[20], sb2;
    for (int t = threadIdx.x; t < 23 * 20; t += blockDim.x) sw[t] = cw[t];
    if (threadIdx.x < 20) { sb[threadIdx.x] = cb[threadIdx.x]; sw2[threadIdx.x] = dw[threadIdx.x]; }
    if (threadIdx.x == 0) sb2 = db[0];
    __syncthreads();
    int i = blockIdx.x * blockDim.x + threadIdx.x;
    if (i >= Md) return;
    const float* h = g_bufA;
    int t = dtar[i];
    float a = darm[i];
    float feat[23];
#pragma unroll
    for (int k = 0; k < 10; k++) feat[k] = h[(size_t)t * NDS + k];
#pragma unroll
    for (int k = 0; k < 12; k++) feat[10 + k] = x1[(size_t)t * 15 + 3 + k];
    feat[22] = a;
    float acc[20];
#pragma unroll
    for (int j = 0; j < 20; j++) acc[j] = sb[j];
#pragma unroll
    for (int k = 0; k < 23; k++) {
        float f = feat[k];
#pragma unroll
        for (int j = 0; j < 20; j++) acc[j] += f * sw[k * 20 + j];
    }
    float sres = sb2;
#pragma unroll
    for (int j = 0; j < 20; j++) { float r = (acc[j] > 0.f) ? acc[j] : 0.f; sres += r * sw2[j]; }
    atomicAdd(&g_p[dmove[i]], sres);
}

// ---------------- value head (h = bufA) ----------------
__global__ void k_value(const float* __restrict__ x1, const float* __restrict__ x2,
                        const float* __restrict__ w1, const float* __restrict__ b1,
                        const float* __restrict__ w2, const float* __restrict__ bias2, int N) {
    __shared__ float sw1[29 * 15], sb1[15], sw2[15], sx2[4], sb2;
    __shared__ float red[256];
    for (int t = threadIdx.x; t < 29 * 15; t += blockDim.x) sw1[t] = w1[t];
    if (threadIdx.x < 15) { sb1[threadIdx.x] = b1[threadIdx.x]; sw2[threadIdx.x] = w2[threadIdx.x]; }
    if (threadIdx.x < 4) sx2[threadIdx.x] = x2[threadIdx.x];
    if (threadIdx.x == 0) sb2 = bias2[0];
    __syncthreads();
    int n = blockIdx.x * blockDim.x + threadIdx.x;
    float v = 0.f;
    if (n < N) {
        const float* h = g_bufA;
        float feat[29];
#pragma unroll
        for (int k = 0; k < 10; k++) feat[k] = h[(size_t)n * NDS + k];
#pragma unroll
        for (int k = 0; k < 15; k++) feat[10 + k] = x1[(size_t)n * 15 + k];
#pragma unroll
        for (int k = 0; k < 4; k++) feat[25 + k] = sx2[k];
        float acc[15];
#pragma unroll
        for (int j = 0; j < 15; j++) acc[j] = sb1[j];
#pragma unroll
        for (int k = 0; k < 29; k++) {
            float f = feat[k];
#pragma unroll
            for (int j = 0; j < 15; j++) acc[j] += f * sw1[k * 15 + j];
        }
        v = sb2;
#pragma unroll
        for (int j = 0; j < 15; j++) { float r = (acc[j] > 0.f) ? acc[j] : 0.f; v += r * sw2[j]; }
    }
    red[threadIdx.x] = v;
    __syncthreads();
    for (int s = 128; s > 0; s >>= 1) {
        if (threadIdx.x < (unsigned)s) red[threadIdx.x] += red[threadIdx.x + s];
        __syncthreads();
    }
    if (threadIdx.x == 0) atomicAdd(&g_vsum[0], red[0]);
}

// -------- finalize (FLOAT32 output): out[0]=V, out[1..M]=log_softmax(p) --------
__global__ void k_final(float* __restrict__ out, int M, int N) {
    __shared__ float red[1024];
    int tid = threadIdx.x;
    float mx = -1e30f;
    for (int i = tid; i < M; i += 1024) mx = fmaxf(mx, g_p[i]);
    red[tid] = mx;
    __syncthreads();
    for (int s = 512; s > 0; s >>= 1) {
        if (tid < s) red[tid] = fmaxf(red[tid], red[tid + s]);
        __syncthreads();
    }
    float pmax = red[0];
    __syncthreads();
    float sm = 0.f;
    for (int i = tid; i < M; i += 1024) sm += __expf(g_p[i] - pmax);
    red[tid] = sm;
    __syncthreads();
    for (int s = 512; s > 0; s >>= 1) {
        if (tid < s) red[tid] += red[tid + s];
        __syncthreads();
    }
    float lse = pmax + logf(red[0]);
    if (tid == 0) out[0] = tanhf(g_vsum[0] / (float)N);
    for (int i = tid; i < M; i += 1024) out[1 + i] = g_p[i] - lse;
}

extern "C" void kernel_launch(void* const* d_in, const int* in_sizes, int n_in,
                              void* d_out, int out_size, void* d_ws, size_t ws_size,
                              hipStream_t stream) {
    // All float inputs AND the output are FLOAT32 (per reference dtypes).
    const float* x1 = (const float*)d_in[0];
    const float* x2 = (const float*)d_in[1];
    const int* edges = (const int*)d_in[2];
    const int* asrc = (const int*)d_in[3];
    const int* adst = (const int*)d_in[4];
    const float* aarm = (const float*)d_in[5];
    const int* amove = (const int*)d_in[6];
    const int* dtar = (const int*)d_in[7];
    const float* darm = (const float*)d_in[8];
    const int* dmove = (const int*)d_in[9];
    const int pb = n_in - 24;   // params are the last 24 inputs
    const float* g1_wl  = (const float*)d_in[pb + 0];
    const float* g1_wr  = (const float*)d_in[pb + 1];
    const float* g1_att = (const float*)d_in[pb + 2];
    const float* g1_b   = (const float*)d_in[pb + 3];
    const float* g2_wl  = (const float*)d_in[pb + 4];
    const float* g2_wr  = (const float*)d_in[pb + 5];
    const float* g2_att = (const float*)d_in[pb + 6];
    const float* g2_b   = (const float*)d_in[pb + 7];
    const float* g3_wl  = (const float*)d_in[pb + 8];
    const float* g3_wr  = (const float*)d_in[pb + 9];
    const float* g3_att = (const float*)d_in[pb + 10];
    const float* g3_b   = (const float*)d_in[pb + 11];
    const float* lin_w  = (const float*)d_in[pb + 12];
    const float* lin_b  = (const float*)d_in[pb + 13];
    const float* lin2_w = (const float*)d_in[pb + 14];
    const float* lin2_b = (const float*)d_in[pb + 15];
    const float* aaa_w  = (const float*)d_in[pb + 16];
    const float* aaa_b  = (const float*)d_in[pb + 17];
    const float* bbb_w  = (const float*)d_in[pb + 18];
    const float* bbb_b  = (const float*)d_in[pb + 19];
    const float* ccc_w  = (const float*)d_in[pb + 20];
    const float* ccc_b  = (const float*)d_in[pb + 21];
    const float* ddd_w  = (const float*)d_in[pb + 22];
    const float* ddd_b  = (const float*)d_in[pb + 23];

    int N = in_sizes[0] / 15;
    const int E = in_sizes[2] / 2;
    const int Ma = in_sizes[3];
    const int Md = in_sizes[7];
    int M = out_size - 1;
    if (N > N_CAP) N = N_CAP;
    if (M > M_CAP) M = M_CAP;
    const int* src = edges;
    const int* dst = edges + E;

    const int nb = (N + 255) / 256;
    const int eb = (E + N + 255) / 256;

    k_init<<<(M + 256) / 256, 256, 0, stream>>>(M);

    // layer 1 -> bufA
    k_gat_pre<<<nb, 256, 0, stream>>>(x1, g1_wl, g1_wr, 15, 0, N);
    k_edge_logit<<<eb, 256, 0, stream>>>(src, dst, g1_att, E, N);
    k_edge_acc<<<eb, 256, 0, stream>>>(src, dst, g1_att, 0, E, N);
    k_gat_post<<<nb, 256, 0, stream>>>(g1_b, 0, N);
    // layer 2: bufA -> bufB
    k_gat_pre<<<nb, 256, 0, stream>>>(x1, g2_wl, g2_wr, 25, 1, N);
    k_edge_logit<<<eb, 256, 0, stream>>>(src, dst, g2_att, E, N);
    k_edge_acc<<<eb, 256, 0, stream>>>(src, dst, g2_att, 1, E, N);
    k_gat_post<<<nb, 256, 0, stream>>>(g2_b, 1, N);
    // layer 3: bufB -> bufA
    k_gat_pre<<<nb, 256, 0, stream>>>(x1, g3_wl, g3_wr, 25, 0, N);
    k_edge_logit<<<eb, 256, 0, stream>>>(src, dst, g3_att, E, N);
    k_edge_acc<<<eb, 256, 0, stream>>>(src, dst, g3_att, 0, E, N);
    k_gat_post<<<nb, 256, 0, stream>>>(g3_b, 0, N);

    k_attack<<<(Ma + 255) / 256, 256, 0, stream>>>(x1, asrc, adst, aarm, amove,
                                                   aaa_w, aaa_b, bbb_w, bbb_b, Ma);
    k_deploy<<<(Md + 255) / 256, 256, 0, stream>>>(x1, dtar, darm, dmove,
                                                   ccc_w, ccc_b, ddd_w, ddd_b, Md);
    k_value<<<nb, 256, 0, stream>>>(x1, x2, lin_w, lin_b, lin2_w, lin2_b, N);
    k_final<<<1, 1024, 0, stream>>>((float*)d_out, M, N);
}

// Round 9
// 1620.032 us; speedup vs baseline: 4.0984x; 4.0984x over previous
//
#include <hip/hip_runtime.h>
#include <hip/hip_bf16.h>

#define HS 12       // stride for h / xl / xr rows (48B, 16B-aligned rows)
#define N_CAP 200000
#define M_CAP 32768
#define E_CAP 3200000

// Static device scratch (sizes fixed by problem spec)
__device__ float g_h [(size_t)N_CAP * HS];
__device__ float g_xl[(size_t)N_CAP * HS];
__device__ float g_xr[(size_t)N_CAP * HS];
__device__ int   g_cnt[N_CAP];
__device__ int   g_off[N_CAP];
__device__ int   g_cur[N_CAP];
__device__ int   g_csrc[E_CAP];   // CSR: src node of each incoming edge, grouped by dst
__device__ float g_p[M_CAP];
__device__ float g_vsum[1];

// ---------------- init: zero p, vsum, cnt ----------------
__global__ void k_init(int M, int N) {
    int i = blockIdx.x * blockDim.x + threadIdx.x;
    if (i < M) g_p[i] = 0.f;
    if (i < N) g_cnt[i] = 0;
    if (i == 0) g_vsum[0] = 0.f;
}

// ---------------- CSR build: histogram of dst ----------------
__global__ void k_hist(const int* __restrict__ dst, int E) {
    int i = blockIdx.x * blockDim.x + threadIdx.x;
    if (i < E) atomicAdd(&g_cnt[dst[i]], 1);
}

// ---------------- CSR build: exclusive scan (single block) ----------------
__global__ void k_scan(int N) {
    __shared__ int s[1024];
    int t = threadIdx.x;
    int chunk = (N + 1023) / 1024;
    int lo = t * chunk, hi = lo + chunk; if (hi > N) hi = N;
    int ts = 0;
    for (int i = lo; i < hi; i++) ts += g_cnt[i];
    s[t] = ts;
    __syncthreads();
    for (int d = 1; d < 1024; d <<= 1) {
        int v = (t >= d) ? s[t - d] : 0;
        __syncthreads();
        s[t] += v;
        __syncthreads();
    }
    int run = s[t] - ts;  // exclusive prefix of this thread's chunk
    for (int i = lo; i < hi; i++) {
        g_off[i] = run;
        g_cur[i] = run;
        run += g_cnt[i];
    }
}

// ---------------- CSR build: scatter src by dst ----------------
__global__ void k_scatter(const int* __restrict__ src, const int* __restrict__ dst, int E) {
    int i = blockIdx.x * blockDim.x + threadIdx.x;
    if (i >= E) return;
    int pos = atomicAdd(&g_cur[dst[i]], 1);
    g_csrc[pos] = src[i];
}

// ---- per-node xl/xr from [hprev|x1] (reads g_h of prev layer when in_dim==25) ----
__global__ void k_gat_pre(const float* __restrict__ x1,
                          const float* __restrict__ wl, const float* __restrict__ wr,
                          int in_dim, int N) {
    __shared__ float swl[250], swr[250];
    for (int t = threadIdx.x; t < in_dim * 10; t += blockDim.x) { swl[t] = wl[t]; swr[t] = wr[t]; }
    __syncthreads();
    int n = blockIdx.x * blockDim.x + threadIdx.x;
    if (n >= N) return;
    float aL[10], aR[10];
#pragma unroll
    for (int j = 0; j < 10; j++) { aL[j] = 0.f; aR[j] = 0.f; }
    int row = 0;
    if (in_dim == 25) {
        for (int k = 0; k < 10; k++) {
            float v = g_h[(size_t)n * HS + k];
#pragma unroll
            for (int j = 0; j < 10; j++) { aL[j] += v * swl[k * 10 + j]; aR[j] += v * swr[k * 10 + j]; }
        }
        row = 10;
    }
    for (int k = 0; k < 15; k++) {
        float v = x1[(size_t)n * 15 + k];
#pragma unroll
        for (int j = 0; j < 10; j++) { aL[j] += v * swl[(row + k) * 10 + j]; aR[j] += v * swr[(row + k) * 10 + j]; }
    }
#pragma unroll
    for (int j = 0; j < 10; j++) { g_xl[(size_t)n * HS + j] = aL[j]; g_xr[(size_t)n * HS + j] = aR[j]; }
}

// ---- per-node gather: online softmax over self-loop + incoming edges; h = relu(num/den + b) ----
__global__ void k_gat_gather(const float* __restrict__ att, const float* __restrict__ b, int N) {
    __shared__ float satt[10], sb[10];
    if (threadIdx.x < 10) { satt[threadIdx.x] = att[threadIdx.x]; sb[threadIdx.x] = b[threadIdx.x]; }
    __syncthreads();
    int n = blockIdx.x * blockDim.x + threadIdx.x;
    if (n >= N) return;
    float xr[10], num[10];
#pragma unroll
    for (int j = 0; j < 10; j++) xr[j] = g_xr[(size_t)n * HS + j];
    // self-loop first (always present)
    float m;   // running max
    {
        float acc = 0.f;
#pragma unroll
        for (int k = 0; k < 10; k++) {
            float xls = g_xl[(size_t)n * HS + k];
            float t = xls + xr[k];
            t = (t > 0.f) ? t : 0.2f * t;
            acc += t * satt[k];
            num[k] = xls;     // weight exp(0)=1
        }
        m = acc;
    }
    float den = 1.f;
    int lo = g_off[n], hi = lo + g_cnt[n];
    for (int e = lo; e < hi; e++) {
        int s = g_csrc[e];
        float xls[10];
#pragma unroll
        for (int k = 0; k < 10; k++) xls[k] = g_xl[(size_t)s * HS + k];
        float acc = 0.f;
#pragma unroll
        for (int k = 0; k < 10; k++) {
            float t = xls[k] + xr[k];
            t = (t > 0.f) ? t : 0.2f * t;
            acc += t * satt[k];
        }
        if (acc > m) {           // rescale running state
            float sc = __expf(m - acc);
            den *= sc;
#pragma unroll
            for (int j = 0; j < 10; j++) num[j] *= sc;
            m = acc;
        }
        float w = __expf(acc - m);
        den += w;
#pragma unroll
        for (int j = 0; j < 10; j++) num[j] += w * xls[j];
    }
    float inv = 1.f / den;
#pragma unroll
    for (int j = 0; j < 10; j++) {
        float v = num[j] * inv + sb[j];
        g_h[(size_t)n * HS + j] = (v > 0.f) ? v : 0.f;
    }
}

// ---------------- attack order scoring ----------------
__global__ void k_attack(const float* __restrict__ x1,
                         const int* __restrict__ asrc, const int* __restrict__ adst,
                         const float* __restrict__ aarm, const int* __restrict__ amove,
                         const float* __restrict__ aw, const float* __restrict__ ab,
                         const float* __restrict__ bw, const float* __restrict__ bb,
                         int Ma) {
    __shared__ float sw[48 * 20], sb[20], sw2[20], sb2;
    for (int t = threadIdx.x; t < 48 * 20; t += blockDim.x) sw[t] = aw[t];
    if (threadIdx.x < 20) { sb[threadIdx.x] = ab[threadIdx.x]; sw2[threadIdx.x] = bw[threadIdx.x]; }
    if (threadIdx.x == 0) sb2 = bb[0];
    __syncthreads();
    int i = blockIdx.x * blockDim.x + threadIdx.x;
    if (i >= Ma) return;
    int s = asrc[i], d = adst[i];
    float a = aarm[i];
    float feat[48];
#pragma unroll
    for (int k = 0; k < 10; k++) feat[k] = g_h[(size_t)s * HS + k];
#pragma unroll
    for (int k = 0; k < 10; k++) feat[10 + k] = g_h[(size_t)d * HS + k];
#pragma unroll
    for (int k = 0; k < 12; k++) feat[20 + k] = x1[(size_t)s * 15 + 3 + k];
#pragma unroll
    for (int k = 0; k < 14; k++) feat[32 + k] = x1[(size_t)d * 15 + 1 + k];
    feat[46] = a;
    feat[47] = 0.6f * a - 0.7f * (x1[(size_t)d * 15 + 3] + x1[(size_t)d * 15 + 4]);
    float acc[20];
#pragma unroll
    for (int j = 0; j < 20; j++) acc[j] = sb[j];
#pragma unroll
    for (int k = 0; k < 48; k++) {
        float f = feat[k];
#pragma unroll
        for (int j = 0; j < 20; j++) acc[j] += f * sw[k * 20 + j];
    }
    float sres = sb2;
#pragma unroll
    for (int j = 0; j < 20; j++) { float r = (acc[j] > 0.f) ? acc[j] : 0.f; sres += r * sw2[j]; }
    atomicAdd(&g_p[amove[i]], sres);
}

// ---------------- deploy order scoring ----------------
__global__ void k_deploy(const float* __restrict__ x1,
                         const int* __restrict__ dtar, const float* __restrict__ darm,
                         const int* __restrict__ dmove,
                         const float* __restrict__ cw, const float* __restrict__ cb,
                         const float* __restrict__ dw, const float* __restrict__ db,
                         int Md) {
    __shared__ float sw[23 * 20], sb[20], sw2[20], sb2;
    for (int t = threadIdx.x; t < 23 * 20; t += blockDim.x) sw[t] = cw[t];
    if (threadIdx.x < 20) { sb[threadIdx.x] = cb[threadIdx.x]; sw2[threadIdx.x] = dw[threadIdx.x]; }
    if (threadIdx.x == 0) sb2 = db[0];
    __syncthreads();
    int i = blockIdx.x * blockDim.x + threadIdx.x;
    if (i >= Md) return;
    int t = dtar[i];
    float a = darm[i];
    float feat[23];
#pragma unroll
    for (int k = 0; k < 10; k++) feat[k] = g_h[(size_t)t * HS + k];
#pragma unroll
    for (int k = 0; k < 12; k++) feat[10 + k] = x1[(size_t)t * 15 + 3 + k];
    feat[22] = a;
    float acc[20];
#pragma unroll
    for (int j = 0; j < 20; j++) acc[j] = sb[j];
#pragma unroll
    for (int k = 0; k < 23; k++) {
        float f = feat[k];
#pragma unroll
        for (int j = 0; j < 20; j++) acc[j] += f * sw[k * 20 + j];
    }
    float sres = sb2;
#pragma unroll
    for (int j = 0; j < 20; j++) { float r = (acc[j] > 0.f) ? acc[j] : 0.f; sres += r * sw2[j]; }
    atomicAdd(&g_p[dmove[i]], sres);
}

// ---------------- value head ----------------
__global__ void k_value(const float* __restrict__ x1, const float* __restrict__ x2,
                        const float* __restrict__ w1, const float* __restrict__ b1,
                        const float* __restrict__ w2, const float* __restrict__ bias2, int N) {
    __shared__ float sw1[29 * 15], sb1[15], sw2[15], sx2[4], sb2;
    __shared__ float red[256];
    for (int t = threadIdx.x; t < 29 * 15; t += blockDim.x) sw1[t] = w1[t];
    if (threadIdx.x < 15) { sb1[threadIdx.x] = b1[threadIdx.x]; sw2[threadIdx.x] = w2[threadIdx.x]; }
    if (threadIdx.x < 4) sx2[threadIdx.x] = x2[threadIdx.x];
    if (threadIdx.x == 0) sb2 = bias2[0];
    __syncthreads();
    int n = blockIdx.x * blockDim.x + threadIdx.x;
    float v = 0.f;
    if (n < N) {
        float feat[29];
#pragma unroll
        for (int k = 0; k < 10; k++) feat[k] = g_h[(size_t)n * HS + k];
#pragma unroll
        for (int k = 0; k < 15; k++) feat[10 + k] = x1[(size_t)n * 15 + k];
#pragma unroll
        for (int k = 0; k < 4; k++) feat[25 + k] = sx2[k];
        float acc[15];
#pragma unroll
        for (int j = 0; j < 15; j++) acc[j] = sb1[j];
#pragma unroll
        for (int k = 0; k < 29; k++) {
            float f = feat[k];
#pragma unroll
            for (int j = 0; j < 15; j++) acc[j] += f * sw1[k * 15 + j];
        }
        v = sb2;
#pragma unroll
        for (int j = 0; j < 15; j++) { float r = (acc[j] > 0.f) ? acc[j] : 0.f; v += r * sw2[j]; }
    }
    red[threadIdx.x] = v;
    __syncthreads();
    for (int s = 128; s > 0; s >>= 1) {
        if (threadIdx.x < (unsigned)s) red[threadIdx.x] += red[threadIdx.x + s];
        __syncthreads();
    }
    if (threadIdx.x == 0) atomicAdd(&g_vsum[0], red[0]);
}

// -------- finalize (f32 output): out[0]=V, out[1..M]=log_softmax(p) --------
__global__ void k_final(float* __restrict__ out, int M, int N) {
    __shared__ float red[1024];
    int tid = threadIdx.x;
    float mx = -1e30f;
    for (int i = tid; i < M; i += 1024) mx = fmaxf(mx, g_p[i]);
    red[tid] = mx;
    __syncthreads();
    for (int s = 512; s > 0; s >>= 1) {
        if (tid < s) red[tid] = fmaxf(red[tid], red[tid + s]);
        __syncthreads();
    }
    float pmax = red[0];
    __syncthreads();
    float sm = 0.f;
    for (int i = tid; i < M; i += 1024) sm += __expf(g_p[i] - pmax);
    red[tid] = sm;
    __syncthreads();
    for (int s = 512; s > 0; s >>= 1) {
        if (tid < s) red[tid] += red[tid + s];
        __syncthreads();
    }
    float lse = pmax + logf(red[0]);
    if (tid == 0) out[0] = tanhf(g_vsum[0] / (float)N);
    for (int i = tid; i < M; i += 1024) out[1 + i] = g_p[i] - lse;
}

extern "C" void kernel_launch(void* const* d_in, const int* in_sizes, int n_in,
                              void* d_out, int out_size, void* d_ws, size_t ws_size,
                              hipStream_t stream) {
    const float* x1 = (const float*)d_in[0];
    const float* x2 = (const float*)d_in[1];
    const int* edges = (const int*)d_in[2];
    const int* asrc = (const int*)d_in[3];
    const int* adst = (const int*)d_in[4];
    const float* aarm = (const float*)d_in[5];
    const int* amove = (const int*)d_in[6];
    const int* dtar = (const int*)d_in[7];
    const float* darm = (const float*)d_in[8];
    const int* dmove = (const int*)d_in[9];
    const int pb = n_in - 24;
    const float* g1_wl  = (const float*)d_in[pb + 0];
    const float* g1_wr  = (const float*)d_in[pb + 1];
    const float* g1_att = (const float*)d_in[pb + 2];
    const float* g1_b   = (const float*)d_in[pb + 3];
    const float* g2_wl  = (const float*)d_in[pb + 4];
    const float* g2_wr  = (const float*)d_in[pb + 5];
    const float* g2_att = (const float*)d_in[pb + 6];
    const float* g2_b   = (const float*)d_in[pb + 7];
    const float* g3_wl  = (const float*)d_in[pb + 8];
    const float* g3_wr  = (const float*)d_in[pb + 9];
    const float* g3_att = (const float*)d_in[pb + 10];
    const float* g3_b   = (const float*)d_in[pb + 11];
    const float* lin_w  = (const float*)d_in[pb + 12];
    const float* lin_b  = (const float*)d_in[pb + 13];
    const float* lin2_w = (const float*)d_in[pb + 14];
    const float* lin2_b = (const float*)d_in[pb + 15];
    const float* aaa_w  = (const float*)d_in[pb + 16];
    const float* aaa_b  = (const float*)d_in[pb + 17];
    const float* bbb_w  = (const float*)d_in[pb + 18];
    const float* bbb_b  = (const float*)d_in[pb + 19];
    const float* ccc_w  = (const float*)d_in[pb + 20];
    const float* ccc_b  = (const float*)d_in[pb + 21];
    const float* ddd_w  = (const float*)d_in[pb + 22];
    const float* ddd_b  = (const float*)d_in[pb + 23];

    int N = in_sizes[0] / 15;
    int E = in_sizes[2] / 2;
    const int Ma = in_sizes[3];
    const int Md = in_sizes[7];
    int M = out_size - 1;
    if (N > N_CAP) N = N_CAP;
    if (E > E_CAP) E = E_CAP;
    if (M > M_CAP) M = M_CAP;
    const int* src = edges;
    const int* dst = edges + E;

    const int nb = (N + 255) / 256;
    const int ebE = (E + 255) / 256;
    int mi = M > N ? M : N;

    // init + CSR build (once; reused by all 3 layers)
    k_init<<<(mi + 255) / 256, 256, 0, stream>>>(M, N);
    k_hist<<<ebE, 256, 0, stream>>>(dst, E);
    k_scan<<<1, 1024, 0, stream>>>(N);
    k_scatter<<<ebE, 256, 0, stream>>>(src, dst, E);

    // layer 1
    k_gat_pre<<<nb, 256, 0, stream>>>(x1, g1_wl, g1_wr, 15, N);
    k_gat_gather<<<nb, 256, 0, stream>>>(g1_att, g1_b, N);
    // layer 2
    k_gat_pre<<<nb, 256, 0, stream>>>(x1, g2_wl, g2_wr, 25, N);
    k_gat_gather<<<nb, 256, 0, stream>>>(g2_att, g2_b, N);
    // layer 3
    k_gat_pre<<<nb, 256, 0, stream>>>(x1, g3_wl, g3_wr, 25, N);
    k_gat_gather<<<nb, 256, 0, stream>>>(g3_att, g3_b, N);

    k_attack<<<(Ma + 255) / 256, 256, 0, stream>>>(x1, asrc, adst, aarm, amove,
                                                   aaa_w, aaa_b, bbb_w, bbb_b, Ma);
    k_deploy<<<(Md + 255) / 256, 256, 0, stream>>>(x1, dtar, darm, dmove,
                                                   ccc_w, ccc_b, ddd_w, ddd_b, Md);
    k_value<<<nb, 256, 0, stream>>>(x1, x2, lin_w, lin_b, lin2_w, lin2_b, N);
    k_final<<<1, 1024, 0, stream>>>((float*)d_out, M, N);
}

// Round 10
// 1190.449 us; speedup vs baseline: 5.5774x; 1.3609x over previous
//
#include <hip/hip_runtime.h>
#include <hip/hip_bf16.h>

#define HS 12       // stride for h / xl / xr rows (48B = 3 x float4)
#define N_CAP 200000
#define M_CAP 32768
#define E_CAP 3200000
#define SCAN_B 256

// Static device scratch (16B-aligned rows for float4 gathers)
__device__ __align__(16) float g_h [(size_t)N_CAP * HS];
__device__ __align__(16) float g_xl[(size_t)N_CAP * HS];
__device__ __align__(16) float g_xr[(size_t)N_CAP * HS];
__device__ int   g_cnt[N_CAP];
__device__ int   g_off[N_CAP];
__device__ int   g_cur[N_CAP];
__device__ int   g_bsum[1024];
__device__ int   g_csrc[E_CAP];   // CSR: src node of each incoming edge, grouped by dst
__device__ float g_p[M_CAP];
__device__ float g_vsum[1];

__device__ __forceinline__ void load_row10(const float* row, float* v) {
    const float4* r4 = (const float4*)row;
    float4 a = r4[0], b = r4[1];
    float2 c = ((const float2*)row)[4];
    v[0] = a.x; v[1] = a.y; v[2] = a.z; v[3] = a.w;
    v[4] = b.x; v[5] = b.y; v[6] = b.z; v[7] = b.w;
    v[8] = c.x; v[9] = c.y;
}

// ---------------- init: zero p, vsum, cnt ----------------
__global__ void k_init(int M, int N) {
    int i = blockIdx.x * blockDim.x + threadIdx.x;
    if (i < M) g_p[i] = 0.f;
    if (i < N) g_cnt[i] = 0;
    if (i == 0) g_vsum[0] = 0.f;
}

// ---------------- CSR build: histogram of dst ----------------
__global__ void k_hist(const int* __restrict__ dst, int E) {
    int i = blockIdx.x * blockDim.x + threadIdx.x;
    if (i < E) atomicAdd(&g_cnt[dst[i]], 1);
}

// ---------------- hierarchical exclusive scan, phase 1: block-local ----------------
__global__ void k_scan1(int N) {
    __shared__ int s[SCAN_B];
    int gid = blockIdx.x * SCAN_B + threadIdx.x;
    int v = (gid < N) ? g_cnt[gid] : 0;
    s[threadIdx.x] = v;
    __syncthreads();
    for (int d = 1; d < SCAN_B; d <<= 1) {
        int t = (threadIdx.x >= d) ? s[threadIdx.x - d] : 0;
        __syncthreads();
        s[threadIdx.x] += t;
        __syncthreads();
    }
    if (gid < N) g_off[gid] = s[threadIdx.x] - v;            // exclusive within block
    if (threadIdx.x == SCAN_B - 1) g_bsum[blockIdx.x] = s[threadIdx.x];
}

// ---------------- phase 2: scan of block sums (nb <= 1024) ----------------
__global__ void k_scan2(int nb) {
    __shared__ int s[1024];
    int t = threadIdx.x;
    int v = (t < nb) ? g_bsum[t] : 0;
    s[t] = v;
    __syncthreads();
    for (int d = 1; d < 1024; d <<= 1) {
        int x = (t >= d) ? s[t - d] : 0;
        __syncthreads();
        s[t] += x;
        __syncthreads();
    }
    if (t < nb) g_bsum[t] = s[t] - v;                         // exclusive block offset
}

// ---------------- phase 3: add block offsets ----------------
__global__ void k_scan3(int N) {
    int gid = blockIdx.x * SCAN_B + threadIdx.x;
    if (gid >= N) return;
    int off = g_off[gid] + g_bsum[blockIdx.x];
    g_off[gid] = off;
    g_cur[gid] = off;
}

// ---------------- CSR build: scatter src by dst ----------------
__global__ void k_scatter(const int* __restrict__ src, const int* __restrict__ dst, int E) {
    int i = blockIdx.x * blockDim.x + threadIdx.x;
    if (i >= E) return;
    int pos = atomicAdd(&g_cur[dst[i]], 1);
    g_csrc[pos] = src[i];
}

// ---- per-node xl/xr from [hprev|x1] (reads g_h of prev layer when in_dim==25) ----
__global__ void k_gat_pre(const float* __restrict__ x1,
                          const float* __restrict__ wl, const float* __restrict__ wr,
                          int in_dim, int N) {
    __shared__ float swl[250], swr[250];
    for (int t = threadIdx.x; t < in_dim * 10; t += blockDim.x) { swl[t] = wl[t]; swr[t] = wr[t]; }
    __syncthreads();
    int n = blockIdx.x * blockDim.x + threadIdx.x;
    if (n >= N) return;
    float aL[10], aR[10];
#pragma unroll
    for (int j = 0; j < 10; j++) { aL[j] = 0.f; aR[j] = 0.f; }
    int row = 0;
    if (in_dim == 25) {
        float hv[10];
        load_row10(&g_h[(size_t)n * HS], hv);
        for (int k = 0; k < 10; k++) {
            float v = hv[k];
#pragma unroll
            for (int j = 0; j < 10; j++) { aL[j] += v * swl[k * 10 + j]; aR[j] += v * swr[k * 10 + j]; }
        }
        row = 10;
    }
    for (int k = 0; k < 15; k++) {
        float v = x1[(size_t)n * 15 + k];
#pragma unroll
        for (int j = 0; j < 10; j++) { aL[j] += v * swl[(row + k) * 10 + j]; aR[j] += v * swr[(row + k) * 10 + j]; }
    }
#pragma unroll
    for (int j = 0; j < 10; j++) { g_xl[(size_t)n * HS + j] = aL[j]; g_xr[(size_t)n * HS + j] = aR[j]; }
}

// ---- per-node gather: online softmax over self-loop + incoming edges ----
__global__ void k_gat_gather(const float* __restrict__ att, const float* __restrict__ b, int N) {
    __shared__ float satt[10], sb[10];
    if (threadIdx.x < 10) { satt[threadIdx.x] = att[threadIdx.x]; sb[threadIdx.x] = b[threadIdx.x]; }
    __syncthreads();
    int n = blockIdx.x * blockDim.x + threadIdx.x;
    if (n >= N) return;
    float xr[10], num[10];
    load_row10(&g_xr[(size_t)n * HS], xr);
    float m;   // running max
    {
        float xls[10];
        load_row10(&g_xl[(size_t)n * HS], xls);
        float acc = 0.f;
#pragma unroll
        for (int k = 0; k < 10; k++) {
            float t = xls[k] + xr[k];
            t = (t > 0.f) ? t : 0.2f * t;
            acc += t * satt[k];
            num[k] = xls[k];     // weight exp(0)=1
        }
        m = acc;
    }
    float den = 1.f;
    int lo = g_off[n], hi = lo + g_cnt[n];
    for (int e = lo; e < hi; e++) {
        int s = g_csrc[e];
        float xls[10];
        load_row10(&g_xl[(size_t)s * HS], xls);
        float acc = 0.f;
#pragma unroll
        for (int k = 0; k < 10; k++) {
            float t = xls[k] + xr[k];
            t = (t > 0.f) ? t : 0.2f * t;
            acc += t * satt[k];
        }
        if (acc > m) {           // rescale running state
            float sc = __expf(m - acc);
            den *= sc;
#pragma unroll
            for (int j = 0; j < 10; j++) num[j] *= sc;
            m = acc;
        }
        float w = __expf(acc - m);
        den += w;
#pragma unroll
        for (int j = 0; j < 10; j++) num[j] += w * xls[j];
    }
    float inv = 1.f / den;
#pragma unroll
    for (int j = 0; j < 10; j++) {
        float v = num[j] * inv + sb[j];
        g_h[(size_t)n * HS + j] = (v > 0.f) ? v : 0.f;
    }
}

// ---------------- attack order scoring ----------------
__global__ void k_attack(const float* __restrict__ x1,
                         const int* __restrict__ asrc, const int* __restrict__ adst,
                         const float* __restrict__ aarm, const int* __restrict__ amove,
                         const float* __restrict__ aw, const float* __restrict__ ab,
                         const float* __restrict__ bw, const float* __restrict__ bb,
                         int Ma) {
    __shared__ float sw[48 * 20], sb[20], sw2[20], sb2;
    for (int t = threadIdx.x; t < 48 * 20; t += blockDim.x) sw[t] = aw[t];
    if (threadIdx.x < 20) { sb[threadIdx.x] = ab[threadIdx.x]; sw2[threadIdx.x] = bw[threadIdx.x]; }
    if (threadIdx.x == 0) sb2 = bb[0];
    __syncthreads();
    int i = blockIdx.x * blockDim.x + threadIdx.x;
    if (i >= Ma) return;
    int s = asrc[i], d = adst[i];
    float a = aarm[i];
    float feat[48];
    load_row10(&g_h[(size_t)s * HS], feat);
    load_row10(&g_h[(size_t)d * HS], feat + 10);
#pragma unroll
    for (int k = 0; k < 12; k++) feat[20 + k] = x1[(size_t)s * 15 + 3 + k];
#pragma unroll
    for (int k = 0; k < 14; k++) feat[32 + k] = x1[(size_t)d * 15 + 1 + k];
    feat[46] = a;
    feat[47] = 0.6f * a - 0.7f * (feat[34] + feat[35]);   // x1[d,3], x1[d,4]
    float acc[20];
#pragma unroll
    for (int j = 0; j < 20; j++) acc[j] = sb[j];
#pragma unroll
    for (int k = 0; k < 48; k++) {
        float f = feat[k];
#pragma unroll
        for (int j = 0; j < 20; j++) acc[j] += f * sw[k * 20 + j];
    }
    float sres = sb2;
#pragma unroll
    for (int j = 0; j < 20; j++) { float r = (acc[j] > 0.f) ? acc[j] : 0.f; sres += r * sw2[j]; }
    atomicAdd(&g_p[amove[i]], sres);
}

// ---------------- deploy order scoring ----------------
__global__ void k_deploy(const float* __restrict__ x1,
                         const int* __restrict__ dtar, const float* __restrict__ darm,
                         const int* __restrict__ dmove,
                         const float* __restrict__ cw, const float* __restrict__ cb,
                         const float* __restrict__ dw, const float* __restrict__ db,
                         int Md) {
    __shared__ float sw[23 * 20], sb[20], sw2[20], sb2;
    for (int t = threadIdx.x; t < 23 * 20; t += blockDim.x) sw[t] = cw[t];
    if (threadIdx.x < 20) { sb[threadIdx.x] = cb[threadIdx.x]; sw2[threadIdx.x] = dw[threadIdx.x]; }
    if (threadIdx.x == 0) sb2 = db[0];
    __syncthreads();
    int i = blockIdx.x * blockDim.x + threadIdx.x;
    if (i >= Md) return;
    int t = dtar[i];
    float a = darm[i];
    float feat[23];
    load_row10(&g_h[(size_t)t * HS], feat);
#pragma unroll
    for (int k = 0; k < 12; k++) feat[10 + k] = x1[(size_t)t * 15 + 3 + k];
    feat[22] = a;
    float acc[20];
#pragma unroll
    for (int j = 0; j < 20; j++) acc[j] = sb[j];
#pragma unroll
    for (int k = 0; k < 23; k++) {
        float f = feat[k];
#pragma unroll
        for (int j = 0; j < 20; j++) acc[j] += f * sw[k * 20 + j];
    }
    float sres = sb2;
#pragma unroll
    for (int j = 0; j < 20; j++) { float r = (acc[j] > 0.f) ? acc[j] : 0.f; sres += r * sw2[j]; }
    atomicAdd(&g_p[dmove[i]], sres);
}

// ---------------- value head ----------------
__global__ void k_value(const float* __restrict__ x1, const float* __restrict__ x2,
                        const float* __restrict__ w1, const float* __restrict__ b1,
                        const float* __restrict__ w2, const float* __restrict__ bias2, int N) {
    __shared__ float sw1[29 * 15], sb1[15], sw2[15], sx2[4], sb2;
    __shared__ float red[256];
    for (int t = threadIdx.x; t < 29 * 15; t += blockDim.x) sw1[t] = w1[t];
    if (threadIdx.x < 15) { sb1[threadIdx.x] = b1[threadIdx.x]; sw2[threadIdx.x] = w2[threadIdx.x]; }
    if (threadIdx.x < 4) sx2[threadIdx.x] = x2[threadIdx.x];
    if (threadIdx.x == 0) sb2 = bias2[0];
    __syncthreads();
    int n = blockIdx.x * blockDim.x + threadIdx.x;
    float v = 0.f;
    if (n < N) {
        float feat[29];
        load_row10(&g_h[(size_t)n * HS], feat);
#pragma unroll
        for (int k = 0; k < 15; k++) feat[10 + k] = x1[(size_t)n * 15 + k];
#pragma unroll
        for (int k = 0; k < 4; k++) feat[25 + k] = sx2[k];
        float acc[15];
#pragma unroll
        for (int j = 0; j < 15; j++) acc[j] = sb1[j];
#pragma unroll
        for (int k = 0; k < 29; k++) {
            float f = feat[k];
#pragma unroll
            for (int j = 0; j < 15; j++) acc[j] += f * sw1[k * 15 + j];
        }
        v = sb2;
#pragma unroll
        for (int j = 0; j < 15; j++) { float r = (acc[j] > 0.f) ? acc[j] : 0.f; v += r * sw2[j]; }
    }
    red[threadIdx.x] = v;
    __syncthreads();
    for (int s = 128; s > 0; s >>= 1) {
        if (threadIdx.x < (unsigned)s) red[threadIdx.x] += red[threadIdx.x + s];
        __syncthreads();
    }
    if (threadIdx.x == 0) atomicAdd(&g_vsum[0], red[0]);
}

// -------- finalize (f32 output): out[0]=V, out[1..M]=log_softmax(p) --------
__global__ void k_final(float* __restrict__ out, int M, int N) {
    __shared__ float red[1024];
    int tid = threadIdx.x;
    float mx = -1e30f;
    for (int i = tid; i < M; i += 1024) mx = fmaxf(mx, g_p[i]);
    red[tid] = mx;
    __syncthreads();
    for (int s = 512; s > 0; s >>= 1) {
        if (tid < s) red[tid] = fmaxf(red[tid], red[tid + s]);
        __syncthreads();
    }
    float pmax = red[0];
    __syncthreads();
    float sm = 0.f;
    for (int i = tid; i < M; i += 1024) sm += __expf(g_p[i] - pmax);
    red[tid] = sm;
    __syncthreads();
    for (int s = 512; s > 0; s >>= 1) {
        if (tid < s) red[tid] += red[tid + s];
        __syncthreads();
    }
    float lse = pmax + logf(red[0]);
    if (tid == 0) out[0] = tanhf(g_vsum[0] / (float)N);
    for (int i = tid; i < M; i += 1024) out[1 + i] = g_p[i] - lse;
}

extern "C" void kernel_launch(void* const* d_in, const int* in_sizes, int n_in,
                              void* d_out, int out_size, void* d_ws, size_t ws_size,
                              hipStream_t stream) {
    const float* x1 = (const float*)d_in[0];
    const float* x2 = (const float*)d_in[1];
    const int* edges = (const int*)d_in[2];
    const int* asrc = (const int*)d_in[3];
    const int* adst = (const int*)d_in[4];
    const float* aarm = (const float*)d_in[5];
    const int* amove = (const int*)d_in[6];
    const int* dtar = (const int*)d_in[7];
    const float* darm = (const float*)d_in[8];
    const int* dmove = (const int*)d_in[9];
    const int pb = n_in - 24;
    const float* g1_wl  = (const float*)d_in[pb + 0];
    const float* g1_wr  = (const float*)d_in[pb + 1];
    const float* g1_att = (const float*)d_in[pb + 2];
    const float* g1_b   = (const float*)d_in[pb + 3];
    const float* g2_wl  = (const float*)d_in[pb + 4];
    const float* g2_wr  = (const float*)d_in[pb + 5];
    const float* g2_att = (const float*)d_in[pb + 6];
    const float* g2_b   = (const float*)d_in[pb + 7];
    const float* g3_wl  = (const float*)d_in[pb + 8];
    const float* g3_wr  = (const float*)d_in[pb + 9];
    const float* g3_att = (const float*)d_in[pb + 10];
    const float* g3_b   = (const float*)d_in[pb + 11];
    const float* lin_w  = (const float*)d_in[pb + 12];
    const float* lin_b  = (const float*)d_in[pb + 13];
    const float* lin2_w = (const float*)d_in[pb + 14];
    const float* lin2_b = (const float*)d_in[pb + 15];
    const float* aaa_w  = (const float*)d_in[pb + 16];
    const float* aaa_b  = (const float*)d_in[pb + 17];
    const float* bbb_w  = (const float*)d_in[pb + 18];
    const float* bbb_b  = (const float*)d_in[pb + 19];
    const float* ccc_w  = (const float*)d_in[pb + 20];
    const float* ccc_b  = (const float*)d_in[pb + 21];
    const float* ddd_w  = (const float*)d_in[pb + 22];
    const float* ddd_b  = (const float*)d_in[pb + 23];

    int N = in_sizes[0] / 15;
    int E = in_sizes[2] / 2;
    const int Ma = in_sizes[3];
    const int Md = in_sizes[7];
    int M = out_size - 1;
    if (N > N_CAP) N = N_CAP;
    if (E > E_CAP) E = E_CAP;
    if (M > M_CAP) M = M_CAP;
    const int* src = edges;
    const int* dst = edges + E;

    const int nb = (N + 255) / 256;
    const int ebE = (E + 255) / 256;
    const int nsb = (N + SCAN_B - 1) / SCAN_B;   // scan blocks (<=1024 for N<=262144)
    int mi = M > N ? M : N;

    // init + CSR build (once; reused by all 3 layers)
    k_init<<<(mi + 255) / 256, 256, 0, stream>>>(M, N);
    k_hist<<<ebE, 256, 0, stream>>>(dst, E);
    k_scan1<<<nsb, SCAN_B, 0, stream>>>(N);
    k_scan2<<<1, 1024, 0, stream>>>(nsb);
    k_scan3<<<nsb, SCAN_B, 0, stream>>>(N);
    k_scatter<<<ebE, 256, 0, stream>>>(src, dst, E);

    // layer 1
    k_gat_pre<<<nb, 256, 0, stream>>>(x1, g1_wl, g1_wr, 15, N);
    k_gat_gather<<<nb, 256, 0, stream>>>(g1_att, g1_b, N);
    // layer 2
    k_gat_pre<<<nb, 256, 0, stream>>>(x1, g2_wl, g2_wr, 25, N);
    k_gat_gather<<<nb, 256, 0, stream>>>(g2_att, g2_b, N);
    // layer 3
    k_gat_pre<<<nb, 256, 0, stream>>>(x1, g3_wl, g3_wr, 25, N);
    k_gat_gather<<<nb, 256, 0, stream>>>(g3_att, g3_b, N);

    k_attack<<<(Ma + 255) / 256, 256, 0, stream>>>(x1, asrc, adst, aarm, amove,
                                                   aaa_w, aaa_b, bbb_w, bbb_b, Ma);
    k_deploy<<<(Md + 255) / 256, 256, 0, stream>>>(x1, dtar, darm, dmove,
                                                   ccc_w, ccc_b, ddd_w, ddd_b, Md);
    k_value<<<nb, 256, 0, stream>>>(x1, x2, lin_w, lin_b, lin2_w, lin2_b, N);
    k_final<<<1, 1024, 0, stream>>>((float*)d_out, M, N);
}

// Round 11
// 953.440 us; speedup vs baseline: 6.9638x; 1.2486x over previous
//
#include <hip/hip_runtime.h>
#include <hip/hip_bf16.h>

#define HS 12       // stride for h / xl / xr rows (48B = 3 x float4)
#define N_CAP 200000
#define M_CAP 32768
#define E_CAP 3200000
#define BKS 10      // bucket shift: 1024 nodes per bucket
#define CHUNK 16384 // edges per k_bscatter block

// Static device scratch (16B-aligned rows for float4 gathers)
__device__ __align__(16) float g_h [(size_t)N_CAP * HS];
__device__ __align__(16) float g_xl[(size_t)N_CAP * HS];
__device__ __align__(16) float g_xr[(size_t)N_CAP * HS];
__device__ int   g_cnt[N_CAP];
__device__ int   g_off[N_CAP];
__device__ int   g_bcnt[256];
__device__ int   g_boff[256];
__device__ int   g_bcur[256];
__device__ int2  g_staged[E_CAP]; // (src,dst) pairs grouped by coarse bucket
__device__ int   g_csrc[E_CAP];   // CSR: src of each incoming edge, grouped by dst
__device__ float g_p[M_CAP];
__device__ float g_vsum[1];

__device__ __forceinline__ void load_row10(const float* row, float* v) {
    const float4* r4 = (const float4*)row;
    float4 a = r4[0], b = r4[1];
    float2 c = ((const float2*)row)[4];
    v[0] = a.x; v[1] = a.y; v[2] = a.z; v[3] = a.w;
    v[4] = b.x; v[5] = b.y; v[6] = b.z; v[7] = b.w;
    v[8] = c.x; v[9] = c.y;
}

// ---------------- init: zero p, vsum, bucket counts ----------------
__global__ void k_init(int M) {
    int i = blockIdx.x * blockDim.x + threadIdx.x;
    if (i < M) g_p[i] = 0.f;
    if (i < 256) g_bcnt[i] = 0;
    if (i == M) g_vsum[0] = 0.f;
}

// ---------------- coarse bucket histogram (LDS-aggregated) ----------------
__global__ void k_bhist(const int* __restrict__ dst, int E) {
    __shared__ int hist[256];
    hist[threadIdx.x] = 0;
    __syncthreads();
    for (int e = blockIdx.x * blockDim.x + threadIdx.x; e < E; e += gridDim.x * blockDim.x)
        atomicAdd(&hist[dst[e] >> BKS], 1);
    __syncthreads();
    int v = hist[threadIdx.x];
    if (v) atomicAdd(&g_bcnt[threadIdx.x], v);
}

// ---------------- scan of 256 bucket counts (one block) ----------------
__global__ void k_bscan() {
    __shared__ int s[256];
    int t = threadIdx.x;
    int v = g_bcnt[t];
    s[t] = v;
    __syncthreads();
    for (int d = 1; d < 256; d <<= 1) {
        int x = (t >= d) ? s[t - d] : 0;
        __syncthreads();
        s[t] += x;
        __syncthreads();
    }
    g_boff[t] = s[t] - v;
    g_bcur[t] = s[t] - v;
}

// ---------------- bucket scatter: (src,dst) -> staged, bucket-grouped ----------------
__global__ void k_bscatter(const int* __restrict__ src, const int* __restrict__ dst, int E) {
    __shared__ int hist[256], cur[256];
    int lo = blockIdx.x * CHUNK;
    int hi = lo + CHUNK; if (hi > E) hi = E;
    int tid = threadIdx.x;
    hist[tid] = 0;
    __syncthreads();
    for (int e = lo + tid; e < hi; e += 256) atomicAdd(&hist[dst[e] >> BKS], 1);
    __syncthreads();
    cur[tid] = atomicAdd(&g_bcur[tid], hist[tid]);   // reserve contiguous ranges
    __syncthreads();
    for (int e = lo + tid; e < hi; e += 256) {
        int d = dst[e];
        int pos = atomicAdd(&cur[d >> BKS], 1);
        g_staged[pos] = make_int2(src[e], d);
    }
}

// ------- per-bucket exact grouping: builds g_off/g_cnt/g_csrc (one block/bucket) -------
__global__ void k_bgroup(int N, int E, int nbk) {
    __shared__ int cnt[1024], offl[1024], ssum[256];
    int b = blockIdx.x;
    int nodebase = b << BKS;
    int nnodes = N - nodebase; if (nnodes > 1024) nnodes = 1024;
    int bstart = g_boff[b];
    int bend = (b + 1 < nbk) ? g_boff[b + 1] : E;
    int tid = threadIdx.x;
    for (int j = tid; j < 1024; j += 256) cnt[j] = 0;
    __syncthreads();
    for (int e = bstart + tid; e < bend; e += 256)
        atomicAdd(&cnt[g_staged[e].y - nodebase], 1);
    __syncthreads();
    // exclusive scan of 1024 counts (4 per thread + block scan)
    int s0 = cnt[4 * tid], s1 = cnt[4 * tid + 1], s2 = cnt[4 * tid + 2], s3 = cnt[4 * tid + 3];
    int tsum = s0 + s1 + s2 + s3;
    ssum[tid] = tsum;
    __syncthreads();
    for (int d = 1; d < 256; d <<= 1) {
        int x = (tid >= d) ? ssum[tid - d] : 0;
        __syncthreads();
        ssum[tid] += x;
        __syncthreads();
    }
    int base = ssum[tid] - tsum;
    offl[4 * tid] = base;
    offl[4 * tid + 1] = base + s0;
    offl[4 * tid + 2] = base + s0 + s1;
    offl[4 * tid + 3] = base + s0 + s1 + s2;
    __syncthreads();
    for (int j = tid; j < nnodes; j += 256) {
        g_off[nodebase + j] = bstart + offl[j];
        g_cnt[nodebase + j] = cnt[j];
    }
    __syncthreads();
    for (int j = tid; j < 1024; j += 256) cnt[j] = offl[j];  // repurpose as cursors
    __syncthreads();
    for (int e = bstart + tid; e < bend; e += 256) {
        int2 sd = g_staged[e];
        int p = atomicAdd(&cnt[sd.y - nodebase], 1);
        g_csrc[bstart + p] = sd.x;       // contiguous bucket region: L2-local writes
    }
}

// ---- per-node xl/xr from [hprev|x1] (reads g_h of prev layer when in_dim==25) ----
__global__ void k_gat_pre(const float* __restrict__ x1,
                          const float* __restrict__ wl, const float* __restrict__ wr,
                          int in_dim, int N) {
    __shared__ float swl[250], swr[250];
    for (int t = threadIdx.x; t < in_dim * 10; t += blockDim.x) { swl[t] = wl[t]; swr[t] = wr[t]; }
    __syncthreads();
    int n = blockIdx.x * blockDim.x + threadIdx.x;
    if (n >= N) return;
    float aL[10], aR[10];
#pragma unroll
    for (int j = 0; j < 10; j++) { aL[j] = 0.f; aR[j] = 0.f; }
    int row = 0;
    if (in_dim == 25) {
        float hv[10];
        load_row10(&g_h[(size_t)n * HS], hv);
        for (int k = 0; k < 10; k++) {
            float v = hv[k];
#pragma unroll
            for (int j = 0; j < 10; j++) { aL[j] += v * swl[k * 10 + j]; aR[j] += v * swr[k * 10 + j]; }
        }
        row = 10;
    }
    for (int k = 0; k < 15; k++) {
        float v = x1[(size_t)n * 15 + k];
#pragma unroll
        for (int j = 0; j < 10; j++) { aL[j] += v * swl[(row + k) * 10 + j]; aR[j] += v * swr[(row + k) * 10 + j]; }
    }
#pragma unroll
    for (int j = 0; j < 10; j++) { g_xl[(size_t)n * HS + j] = aL[j]; g_xr[(size_t)n * HS + j] = aR[j]; }
}

// ---- per-node gather: online softmax over self-loop + incoming edges ----
__global__ void k_gat_gather(const float* __restrict__ att, const float* __restrict__ b, int N) {
    __shared__ float satt[10], sb[10];
    if (threadIdx.x < 10) { satt[threadIdx.x] = att[threadIdx.x]; sb[threadIdx.x] = b[threadIdx.x]; }
    __syncthreads();
    int n = blockIdx.x * blockDim.x + threadIdx.x;
    if (n >= N) return;
    float xr[10], num[10];
    load_row10(&g_xr[(size_t)n * HS], xr);
    float m;   // running max
    {
        float xls[10];
        load_row10(&g_xl[(size_t)n * HS], xls);
        float acc = 0.f;
#pragma unroll
        for (int k = 0; k < 10; k++) {
            float t = xls[k] + xr[k];
            t = (t > 0.f) ? t : 0.2f * t;
            acc += t * satt[k];
            num[k] = xls[k];     // weight exp(0)=1
        }
        m = acc;
    }
    float den = 1.f;
    int lo = g_off[n], hi = lo + g_cnt[n];
    for (int e = lo; e < hi; e++) {
        int s = g_csrc[e];
        float xls[10];
        load_row10(&g_xl[(size_t)s * HS], xls);
        float acc = 0.f;
#pragma unroll
        for (int k = 0; k < 10; k++) {
            float t = xls[k] + xr[k];
            t = (t > 0.f) ? t : 0.2f * t;
            acc += t * satt[k];
        }
        if (acc > m) {           // rescale running state
            float sc = __expf(m - acc);
            den *= sc;
#pragma unroll
            for (int j = 0; j < 10; j++) num[j] *= sc;
            m = acc;
        }
        float w = __expf(acc - m);
        den += w;
#pragma unroll
        for (int j = 0; j < 10; j++) num[j] += w * xls[j];
    }
    float inv = 1.f / den;
#pragma unroll
    for (int j = 0; j < 10; j++) {
        float v = num[j] * inv + sb[j];
        g_h[(size_t)n * HS + j] = (v > 0.f) ? v : 0.f;
    }
}

// ---------------- attack order scoring ----------------
__global__ void k_attack(const float* __restrict__ x1,
                         const int* __restrict__ asrc, const int* __restrict__ adst,
                         const float* __restrict__ aarm, const int* __restrict__ amove,
                         const float* __restrict__ aw, const float* __restrict__ ab,
                         const float* __restrict__ bw, const float* __restrict__ bb,
                         int Ma) {
    __shared__ float sw[48 * 20], sb[20], sw2[20], sb2;
    for (int t = threadIdx.x; t < 48 * 20; t += blockDim.x) sw[t] = aw[t];
    if (threadIdx.x < 20) { sb[threadIdx.x] = ab[threadIdx.x]; sw2[threadIdx.x] = bw[threadIdx.x]; }
    if (threadIdx.x == 0) sb2 = bb[0];
    __syncthreads();
    int i = blockIdx.x * blockDim.x + threadIdx.x;
    if (i >= Ma) return;
    int s = asrc[i], d = adst[i];
    float a = aarm[i];
    float feat[48];
    load_row10(&g_h[(size_t)s * HS], feat);
    load_row10(&g_h[(size_t)d * HS], feat + 10);
#pragma unroll
    for (int k = 0; k < 12; k++) feat[20 + k] = x1[(size_t)s * 15 + 3 + k];
#pragma unroll
    for (int k = 0; k < 14; k++) feat[32 + k] = x1[(size_t)d * 15 + 1 + k];
    feat[46] = a;
    feat[47] = 0.6f * a - 0.7f * (feat[34] + feat[35]);   // x1[d,3], x1[d,4]
    float acc[20];
#pragma unroll
    for (int j = 0; j < 20; j++) acc[j] = sb[j];
#pragma unroll
    for (int k = 0; k < 48; k++) {
        float f = feat[k];
#pragma unroll
        for (int j = 0; j < 20; j++) acc[j] += f * sw[k * 20 + j];
    }
    float sres = sb2;
#pragma unroll
    for (int j = 0; j < 20; j++) { float r = (acc[j] > 0.f) ? acc[j] : 0.f; sres += r * sw2[j]; }
    atomicAdd(&g_p[amove[i]], sres);
}

// ---------------- deploy order scoring ----------------
__global__ void k_deploy(const float* __restrict__ x1,
                         const int* __restrict__ dtar, const float* __restrict__ darm,
                         const int* __restrict__ dmove,
                         const float* __restrict__ cw, const float* __restrict__ cb,
                         const float* __restrict__ dw, const float* __restrict__ db,
                         int Md) {
    __shared__ float sw[23 * 20], sb[20], sw2[20], sb2;
    for (int t = threadIdx.x; t < 23 * 20; t += blockDim.x) sw[t] = cw[t];
    if (threadIdx.x < 20) { sb[threadIdx.x] = cb[threadIdx.x]; sw2[threadIdx.x] = dw[threadIdx.x]; }
    if (threadIdx.x == 0) sb2 = db[0];
    __syncthreads();
    int i = blockIdx.x * blockDim.x + threadIdx.x;
    if (i >= Md) return;
    int t = dtar[i];
    float a = darm[i];
    float feat[23];
    load_row10(&g_h[(size_t)t * HS], feat);
#pragma unroll
    for (int k = 0; k < 12; k++) feat[10 + k] = x1[(size_t)t * 15 + 3 + k];
    feat[22] = a;
    float acc[20];
#pragma unroll
    for (int j = 0; j < 20; j++) acc[j] = sb[j];
#pragma unroll
    for (int k = 0; k < 23; k++) {
        float f = feat[k];
#pragma unroll
        for (int j = 0; j < 20; j++) acc[j] += f * sw[k * 20 + j];
    }
    float sres = sb2;
#pragma unroll
    for (int j = 0; j < 20; j++) { float r = (acc[j] > 0.f) ? acc[j] : 0.f; sres += r * sw2[j]; }
    atomicAdd(&g_p[dmove[i]], sres);
}

// ---------------- value head ----------------
__global__ void k_value(const float* __restrict__ x1, const float* __restrict__ x2,
                        const float* __restrict__ w1, const float* __restrict__ b1,
                        const float* __restrict__ w2, const float* __restrict__ bias2, int N) {
    __shared__ float sw1[29 * 15], sb1[15], sw2[15], sx2[4], sb2;
    __shared__ float red[256];
    for (int t = threadIdx.x; t < 29 * 15; t += blockDim.x) sw1[t] = w1[t];
    if (threadIdx.x < 15) { sb1[threadIdx.x] = b1[threadIdx.x]; sw2[threadIdx.x] = w2[threadIdx.x]; }
    if (threadIdx.x < 4) sx2[threadIdx.x] = x2[threadIdx.x];
    if (threadIdx.x == 0) sb2 = bias2[0];
    __syncthreads();
    int n = blockIdx.x * blockDim.x + threadIdx.x;
    float v = 0.f;
    if (n < N) {
        float feat[29];
        load_row10(&g_h[(size_t)n * HS], feat);
#pragma unroll
        for (int k = 0; k < 15; k++) feat[10 + k] = x1[(size_t)n * 15 + k];
#pragma unroll
        for (int k = 0; k < 4; k++) feat[25 + k] = sx2[k];
        float acc[15];
#pragma unroll
        for (int j = 0; j < 15; j++) acc[j] = sb1[j];
#pragma unroll
        for (int k = 0; k < 29; k++) {
            float f = feat[k];
#pragma unroll
            for (int j = 0; j < 15; j++) acc[j] += f * sw1[k * 15 + j];
        }
        v = sb2;
#pragma unroll
        for (int j = 0; j < 15; j++) { float r = (acc[j] > 0.f) ? acc[j] : 0.f; v += r * sw2[j]; }
    }
    red[threadIdx.x] = v;
    __syncthreads();
    for (int s = 128; s > 0; s >>= 1) {
        if (threadIdx.x < (unsigned)s) red[threadIdx.x] += red[threadIdx.x + s];
        __syncthreads();
    }
    if (threadIdx.x == 0) atomicAdd(&g_vsum[0], red[0]);
}

// -------- finalize (f32 output): out[0]=V, out[1..M]=log_softmax(p) --------
__global__ void k_final(float* __restrict__ out, int M, int N) {
    __shared__ float red[1024];
    int tid = threadIdx.x;
    float mx = -1e30f;
    for (int i = tid; i < M; i += 1024) mx = fmaxf(mx, g_p[i]);
    red[tid] = mx;
    __syncthreads();
    for (int s = 512; s > 0; s >>= 1) {
        if (tid < s) red[tid] = fmaxf(red[tid], red[tid + s]);
        __syncthreads();
    }
    float pmax = red[0];
    __syncthreads();
    float sm = 0.f;
    for (int i = tid; i < M; i += 1024) sm += __expf(g_p[i] - pmax);
    red[tid] = sm;
    __syncthreads();
    for (int s = 512; s > 0; s >>= 1) {
        if (tid < s) red[tid] += red[tid + s];
        __syncthreads();
    }
    float lse = pmax + logf(red[0]);
    if (tid == 0) out[0] = tanhf(g_vsum[0] / (float)N);
    for (int i = tid; i < M; i += 1024) out[1 + i] = g_p[i] - lse;
}

extern "C" void kernel_launch(void* const* d_in, const int* in_sizes, int n_in,
                              void* d_out, int out_size, void* d_ws, size_t ws_size,
                              hipStream_t stream) {
    const float* x1 = (const float*)d_in[0];
    const float* x2 = (const float*)d_in[1];
    const int* edges = (const int*)d_in[2];
    const int* asrc = (const int*)d_in[3];
    const int* adst = (const int*)d_in[4];
    const float* aarm = (const float*)d_in[5];
    const int* amove = (const int*)d_in[6];
    const int* dtar = (const int*)d_in[7];
    const float* darm = (const float*)d_in[8];
    const int* dmove = (const int*)d_in[9];
    const int pb = n_in - 24;
    const float* g1_wl  = (const float*)d_in[pb + 0];
    const float* g1_wr  = (const float*)d_in[pb + 1];
    const float* g1_att = (const float*)d_in[pb + 2];
    const float* g1_b   = (const float*)d_in[pb + 3];
    const float* g2_wl  = (const float*)d_in[pb + 4];
    const float* g2_wr  = (const float*)d_in[pb + 5];
    const float* g2_att = (const float*)d_in[pb + 6];
    const float* g2_b   = (const float*)d_in[pb + 7];
    const float* g3_wl  = (const float*)d_in[pb + 8];
    const float* g3_wr  = (const float*)d_in[pb + 9];
    const float* g3_att = (const float*)d_in[pb + 10];
    const float* g3_b   = (const float*)d_in[pb + 11];
    const float* lin_w  = (const float*)d_in[pb + 12];
    const float* lin_b  = (const float*)d_in[pb + 13];
    const float* lin2_w = (const float*)d_in[pb + 14];
    const float* lin2_b = (const float*)d_in[pb + 15];
    const float* aaa_w  = (const float*)d_in[pb + 16];
    const float* aaa_b  = (const float*)d_in[pb + 17];
    const float* bbb_w  = (const float*)d_in[pb + 18];
    const float* bbb_b  = (const float*)d_in[pb + 19];
    const float* ccc_w  = (const float*)d_in[pb + 20];
    const float* ccc_b  = (const float*)d_in[pb + 21];
    const float* ddd_w  = (const float*)d_in[pb + 22];
    const float* ddd_b  = (const float*)d_in[pb + 23];

    int N = in_sizes[0] / 15;
    int E = in_sizes[2] / 2;
    const int Ma = in_sizes[3];
    const int Md = in_sizes[7];
    int M = out_size - 1;
    if (N > N_CAP) N = N_CAP;
    if (E > E_CAP) E = E_CAP;
    if (M > M_CAP) M = M_CAP;
    const int* src = edges;
    const int* dst = edges + E;

    const int nb = (N + 255) / 256;
    const int nbk = (N + 1023) >> BKS;            // coarse buckets (<=196 for N<=200k)
    const int nsc = (E + CHUNK - 1) / CHUNK;      // scatter blocks

    // init + locality-aware CSR build (once; reused by all 3 layers)
    k_init<<<(M + 256) / 256, 256, 0, stream>>>(M);
    k_bhist<<<256, 256, 0, stream>>>(dst, E);
    k_bscan<<<1, 256, 0, stream>>>();
    k_bscatter<<<nsc, 256, 0, stream>>>(src, dst, E);
    k_bgroup<<<nbk, 256, 0, stream>>>(N, E, nbk);

    // layer 1
    k_gat_pre<<<nb, 256, 0, stream>>>(x1, g1_wl, g1_wr, 15, N);
    k_gat_gather<<<nb, 256, 0, stream>>>(g1_att, g1_b, N);
    // layer 2
    k_gat_pre<<<nb, 256, 0, stream>>>(x1, g2_wl, g2_wr, 25, N);
    k_gat_gather<<<nb, 256, 0, stream>>>(g2_att, g2_b, N);
    // layer 3
    k_gat_pre<<<nb, 256, 0, stream>>>(x1, g3_wl, g3_wr, 25, N);
    k_gat_gather<<<nb, 256, 0, stream>>>(g3_att, g3_b, N);

    k_attack<<<(Ma + 255) / 256, 256, 0, stream>>>(x1, asrc, adst, aarm, amove,
                                                   aaa_w, aaa_b, bbb_w, bbb_b, Ma);
    k_deploy<<<(Md + 255) / 256, 256, 0, stream>>>(x1, dtar, darm, dmove,
                                                   ccc_w, ccc_b, ddd_w, ddd_b, Md);
    k_value<<<nb, 256, 0, stream>>>(x1, x2, lin_w, lin_b, lin2_w, lin2_b, N);
    k_final<<<1, 1024, 0, stream>>>((float*)d_out, M, N);
}

// Round 12
// 789.945 us; speedup vs baseline: 8.4051x; 1.2070x over previous
//
#include <hip/hip_runtime.h>
#include <hip/hip_bf16.h>

#define HS 12       // stride for h / xl / xr rows (48B = 3 x float4)
#define US 20       // stride for pre-projected score rows (80B = 5 x float4)
#define N_CAP 200000
#define M_CAP 32768
#define E_CAP 3200000
#define BKS 10      // bucket shift: 1024 nodes per bucket
#define CHUNK 16384 // edges per k_bscatter block

// Static device scratch (16B-aligned rows for float4 gathers)
__device__ __align__(16) float g_h [(size_t)N_CAP * HS];
__device__ __align__(16) float g_xl[(size_t)N_CAP * HS];
__device__ __align__(16) float g_xr[(size_t)N_CAP * HS];
__device__ __align__(16) float g_us[(size_t)N_CAP * US];  // attack source-role projection
__device__ __align__(16) float g_ud[(size_t)N_CAP * US];  // attack dest-role projection (extra folded)
__device__ __align__(16) float g_ut[(size_t)N_CAP * US];  // deploy target projection
__device__ int   g_cnt[N_CAP];
__device__ int   g_off[N_CAP];
__device__ int   g_bcnt[256];
__device__ int   g_boff[256];
__device__ int   g_bcur[256];
__device__ int2  g_staged[E_CAP]; // (src,dst) pairs grouped by coarse bucket
__device__ int   g_csrc[E_CAP];   // CSR: src of each incoming edge, grouped by dst
__device__ float g_p[M_CAP];
__device__ float g_vsum[1];

__device__ __forceinline__ void load_row10(const float* row, float* v) {
    const float4* r4 = (const float4*)row;
    float4 a = r4[0], b = r4[1];
    float2 c = ((const float2*)row)[4];
    v[0] = a.x; v[1] = a.y; v[2] = a.z; v[3] = a.w;
    v[4] = b.x; v[5] = b.y; v[6] = b.z; v[7] = b.w;
    v[8] = c.x; v[9] = c.y;
}
__device__ __forceinline__ void load_row20(const float* row, float* v) {
    const float4* r4 = (const float4*)row;
#pragma unroll
    for (int q = 0; q < 5; q++) {
        float4 a = r4[q];
        v[4 * q] = a.x; v[4 * q + 1] = a.y; v[4 * q + 2] = a.z; v[4 * q + 3] = a.w;
    }
}

// ---------------- init: zero p, vsum, bucket counts ----------------
__global__ void k_init(int M) {
    int i = blockIdx.x * blockDim.x + threadIdx.x;
    if (i < M) g_p[i] = 0.f;
    if (i < 256) g_bcnt[i] = 0;
    if (i == M) g_vsum[0] = 0.f;
}

// ---------------- coarse bucket histogram (LDS-aggregated) ----------------
__global__ void k_bhist(const int* __restrict__ dst, int E) {
    __shared__ int hist[256];
    hist[threadIdx.x] = 0;
    __syncthreads();
    for (int e = blockIdx.x * blockDim.x + threadIdx.x; e < E; e += gridDim.x * blockDim.x)
        atomicAdd(&hist[dst[e] >> BKS], 1);
    __syncthreads();
    int v = hist[threadIdx.x];
    if (v) atomicAdd(&g_bcnt[threadIdx.x], v);
}

// ---------------- scan of 256 bucket counts (one block) ----------------
__global__ void k_bscan() {
    __shared__ int s[256];
    int t = threadIdx.x;
    int v = g_bcnt[t];
    s[t] = v;
    __syncthreads();
    for (int d = 1; d < 256; d <<= 1) {
        int x = (t >= d) ? s[t - d] : 0;
        __syncthreads();
        s[t] += x;
        __syncthreads();
    }
    g_boff[t] = s[t] - v;
    g_bcur[t] = s[t] - v;
}

// ---------------- bucket scatter: (src,dst) -> staged, bucket-grouped ----------------
__global__ void k_bscatter(const int* __restrict__ src, const int* __restrict__ dst, int E) {
    __shared__ int hist[256], cur[256];
    int lo = blockIdx.x * CHUNK;
    int hi = lo + CHUNK; if (hi > E) hi = E;
    int tid = threadIdx.x;
    hist[tid] = 0;
    __syncthreads();
    for (int e = lo + tid; e < hi; e += 256) atomicAdd(&hist[dst[e] >> BKS], 1);
    __syncthreads();
    cur[tid] = atomicAdd(&g_bcur[tid], hist[tid]);   // reserve contiguous ranges
    __syncthreads();
    for (int e = lo + tid; e < hi; e += 256) {
        int d = dst[e];
        int pos = atomicAdd(&cur[d >> BKS], 1);
        g_staged[pos] = make_int2(src[e], d);
    }
}

// ------- per-bucket exact grouping: builds g_off/g_cnt/g_csrc (one block/bucket) -------
__global__ void k_bgroup(int N, int E, int nbk) {
    __shared__ int cnt[1024], offl[1024], ssum[256];
    int b = blockIdx.x;
    int nodebase = b << BKS;
    int nnodes = N - nodebase; if (nnodes > 1024) nnodes = 1024;
    int bstart = g_boff[b];
    int bend = (b + 1 < nbk) ? g_boff[b + 1] : E;
    int tid = threadIdx.x;
    for (int j = tid; j < 1024; j += 256) cnt[j] = 0;
    __syncthreads();
    for (int e = bstart + tid; e < bend; e += 256)
        atomicAdd(&cnt[g_staged[e].y - nodebase], 1);
    __syncthreads();
    int s0 = cnt[4 * tid], s1 = cnt[4 * tid + 1], s2 = cnt[4 * tid + 2], s3 = cnt[4 * tid + 3];
    int tsum = s0 + s1 + s2 + s3;
    ssum[tid] = tsum;
    __syncthreads();
    for (int d = 1; d < 256; d <<= 1) {
        int x = (tid >= d) ? ssum[tid - d] : 0;
        __syncthreads();
        ssum[tid] += x;
        __syncthreads();
    }
    int base = ssum[tid] - tsum;
    offl[4 * tid] = base;
    offl[4 * tid + 1] = base + s0;
    offl[4 * tid + 2] = base + s0 + s1;
    offl[4 * tid + 3] = base + s0 + s1 + s2;
    __syncthreads();
    for (int j = tid; j < nnodes; j += 256) {
        g_off[nodebase + j] = bstart + offl[j];
        g_cnt[nodebase + j] = cnt[j];
    }
    __syncthreads();
    for (int j = tid; j < 1024; j += 256) cnt[j] = offl[j];  // repurpose as cursors
    __syncthreads();
    for (int e = bstart + tid; e < bend; e += 256) {
        int2 sd = g_staged[e];
        int p = atomicAdd(&cnt[sd.y - nodebase], 1);
        g_csrc[bstart + p] = sd.x;       // contiguous bucket region: L2-local writes
    }
}

// ---- per-node xl/xr from [hprev|x1] (reads g_h of prev layer when in_dim==25) ----
__global__ void k_gat_pre(const float* __restrict__ x1,
                          const float* __restrict__ wl, const float* __restrict__ wr,
                          int in_dim, int N) {
    __shared__ float swl[250], swr[250];
    for (int t = threadIdx.x; t < in_dim * 10; t += blockDim.x) { swl[t] = wl[t]; swr[t] = wr[t]; }
    __syncthreads();
    int n = blockIdx.x * blockDim.x + threadIdx.x;
    if (n >= N) return;
    float aL[10], aR[10];
#pragma unroll
    for (int j = 0; j < 10; j++) { aL[j] = 0.f; aR[j] = 0.f; }
    int row = 0;
    if (in_dim == 25) {
        float hv[10];
        load_row10(&g_h[(size_t)n * HS], hv);
        for (int k = 0; k < 10; k++) {
            float v = hv[k];
#pragma unroll
            for (int j = 0; j < 10; j++) { aL[j] += v * swl[k * 10 + j]; aR[j] += v * swr[k * 10 + j]; }
        }
        row = 10;
    }
    for (int k = 0; k < 15; k++) {
        float v = x1[(size_t)n * 15 + k];
#pragma unroll
        for (int j = 0; j < 10; j++) { aL[j] += v * swl[(row + k) * 10 + j]; aR[j] += v * swr[(row + k) * 10 + j]; }
    }
#pragma unroll
    for (int j = 0; j < 10; j++) { g_xl[(size_t)n * HS + j] = aL[j]; g_xr[(size_t)n * HS + j] = aR[j]; }
}

// ---- per-node gather: online softmax over self-loop + incoming edges ----
__global__ void k_gat_gather(const float* __restrict__ att, const float* __restrict__ b, int N) {
    __shared__ float satt[10], sb[10];
    if (threadIdx.x < 10) { satt[threadIdx.x] = att[threadIdx.x]; sb[threadIdx.x] = b[threadIdx.x]; }
    __syncthreads();
    int n = blockIdx.x * blockDim.x + threadIdx.x;
    if (n >= N) return;
    float xr[10], num[10];
    load_row10(&g_xr[(size_t)n * HS], xr);
    float m;   // running max
    {
        float xls[10];
        load_row10(&g_xl[(size_t)n * HS], xls);
        float acc = 0.f;
#pragma unroll
        for (int k = 0; k < 10; k++) {
            float t = xls[k] + xr[k];
            t = (t > 0.f) ? t : 0.2f * t;
            acc += t * satt[k];
            num[k] = xls[k];     // weight exp(0)=1
        }
        m = acc;
    }
    float den = 1.f;
    int lo = g_off[n], hi = lo + g_cnt[n];
    for (int e = lo; e < hi; e++) {
        int s = g_csrc[e];
        float xls[10];
        load_row10(&g_xl[(size_t)s * HS], xls);
        float acc = 0.f;
#pragma unroll
        for (int k = 0; k < 10; k++) {
            float t = xls[k] + xr[k];
            t = (t > 0.f) ? t : 0.2f * t;
            acc += t * satt[k];
        }
        if (acc > m) {           // rescale running state
            float sc = __expf(m - acc);
            den *= sc;
#pragma unroll
            for (int j = 0; j < 10; j++) num[j] *= sc;
            m = acc;
        }
        float w = __expf(acc - m);
        den += w;
#pragma unroll
        for (int j = 0; j < 10; j++) num[j] += w * xls[j];
    }
    float inv = 1.f / den;
#pragma unroll
    for (int j = 0; j < 10; j++) {
        float v = num[j] * inv + sb[j];
        g_h[(size_t)n * HS + j] = (v > 0.f) ? v : 0.f;
    }
}

// ---- pre-project per-node features into score space (runs once after layer 3) ----
// u_s[n] = A[0:10]^T h[n] + A[20:32]^T x1[n,3:15]
// u_d[n] = A[10:20]^T h[n] + A[32:46]^T x1[n,1:15] - 0.7*(x1[n,3]+x1[n,4])*A[47]
// u_t[n] = C[0:10]^T h[n] + C[10:22]^T x1[n,3:15]
__global__ void k_prep(const float* __restrict__ x1,
                       const float* __restrict__ aw, const float* __restrict__ cw, int N) {
    __shared__ float sA[48 * 20], sC[23 * 20];
    for (int t = threadIdx.x; t < 48 * 20; t += blockDim.x) sA[t] = aw[t];
    for (int t = threadIdx.x; t < 23 * 20; t += blockDim.x) sC[t] = cw[t];
    __syncthreads();
    int n = blockIdx.x * blockDim.x + threadIdx.x;
    if (n >= N) return;
    float hv[10], xv[15];
    load_row10(&g_h[(size_t)n * HS], hv);
#pragma unroll
    for (int k = 0; k < 15; k++) xv[k] = x1[(size_t)n * 15 + k];
    float us[20], ud[20], ut[20];
#pragma unroll
    for (int j = 0; j < 20; j++) { us[j] = 0.f; ud[j] = 0.f; ut[j] = 0.f; }
    for (int k = 0; k < 10; k++) {
        float h = hv[k];
#pragma unroll
        for (int j = 0; j < 20; j++) {
            us[j] += h * sA[k * 20 + j];
            ud[j] += h * sA[(10 + k) * 20 + j];
            ut[j] += h * sC[k * 20 + j];
        }
    }
    for (int k = 0; k < 12; k++) {
        float v = xv[3 + k];
#pragma unroll
        for (int j = 0; j < 20; j++) {
            us[j] += v * sA[(20 + k) * 20 + j];
            ut[j] += v * sC[(10 + k) * 20 + j];
        }
    }
    for (int k = 0; k < 14; k++) {
        float v = xv[1 + k];
#pragma unroll
        for (int j = 0; j < 20; j++) ud[j] += v * sA[(32 + k) * 20 + j];
    }
    float t34 = -0.7f * (xv[3] + xv[4]);
#pragma unroll
    for (int j = 0; j < 20; j++) ud[j] += t34 * sA[47 * 20 + j];
#pragma unroll
    for (int j = 0; j < 20; j++) {
        g_us[(size_t)n * US + j] = us[j];
        g_ud[(size_t)n * US + j] = ud[j];
        g_ut[(size_t)n * US + j] = ut[j];
    }
}

// ---------------- attack order scoring (pre-projected) ----------------
__global__ void k_attack(const int* __restrict__ asrc, const int* __restrict__ adst,
                         const float* __restrict__ aarm, const int* __restrict__ amove,
                         const float* __restrict__ aw, const float* __restrict__ ab,
                         const float* __restrict__ bw, const float* __restrict__ bb,
                         int Ma) {
    __shared__ float swa[20], sab[20], sw2[20], sb2;
    if (threadIdx.x < 20) {
        swa[threadIdx.x] = aw[46 * 20 + threadIdx.x] + 0.6f * aw[47 * 20 + threadIdx.x];
        sab[threadIdx.x] = ab[threadIdx.x];
        sw2[threadIdx.x] = bw[threadIdx.x];
    }
    if (threadIdx.x == 0) sb2 = bb[0];
    __syncthreads();
    int i = blockIdx.x * blockDim.x + threadIdx.x;
    if (i >= Ma) return;
    int s = asrc[i], d = adst[i];
    float a = aarm[i];
    float us[20], ud[20];
    load_row20(&g_us[(size_t)s * US], us);
    load_row20(&g_ud[(size_t)d * US], ud);
    float sres = sb2;
#pragma unroll
    for (int j = 0; j < 20; j++) {
        float acc = sab[j] + us[j] + ud[j] + a * swa[j];
        float r = (acc > 0.f) ? acc : 0.f;
        sres += r * sw2[j];
    }
    atomicAdd(&g_p[amove[i]], sres);
}

// ---------------- deploy order scoring (pre-projected) ----------------
__global__ void k_deploy(const int* __restrict__ dtar, const float* __restrict__ darm,
                         const int* __restrict__ dmove,
                         const float* __restrict__ cw, const float* __restrict__ cb,
                         const float* __restrict__ dw, const float* __restrict__ db,
                         int Md) {
    __shared__ float swa[20], scb[20], sw2[20], sb2;
    if (threadIdx.x < 20) {
        swa[threadIdx.x] = cw[22 * 20 + threadIdx.x];
        scb[threadIdx.x] = cb[threadIdx.x];
        sw2[threadIdx.x] = dw[threadIdx.x];
    }
    if (threadIdx.x == 0) sb2 = db[0];
    __syncthreads();
    int i = blockIdx.x * blockDim.x + threadIdx.x;
    if (i >= Md) return;
    int t = dtar[i];
    float a = darm[i];
    float ut[20];
    load_row20(&g_ut[(size_t)t * US], ut);
    float sres = sb2;
#pragma unroll
    for (int j = 0; j < 20; j++) {
        float acc = scb[j] + ut[j] + a * swa[j];
        float r = (acc > 0.f) ? acc : 0.f;
        sres += r * sw2[j];
    }
    atomicAdd(&g_p[dmove[i]], sres);
}

// ---------------- value head ----------------
__global__ void k_value(const float* __restrict__ x1, const float* __restrict__ x2,
                        const float* __restrict__ w1, const float* __restrict__ b1,
                        const float* __restrict__ w2, const float* __restrict__ bias2, int N) {
    __shared__ float sw1[29 * 15], sb1[15], sw2[15], sx2[4], sb2;
    __shared__ float red[256];
    for (int t = threadIdx.x; t < 29 * 15; t += blockDim.x) sw1[t] = w1[t];
    if (threadIdx.x < 15) { sb1[threadIdx.x] = b1[threadIdx.x]; sw2[threadIdx.x] = w2[threadIdx.x]; }
    if (threadIdx.x < 4) sx2[threadIdx.x] = x2[threadIdx.x];
    if (threadIdx.x == 0) sb2 = bias2[0];
    __syncthreads();
    int n = blockIdx.x * blockDim.x + threadIdx.x;
    float v = 0.f;
    if (n < N) {
        float feat[29];
        load_row10(&g_h[(size_t)n * HS], feat);
#pragma unroll
        for (int k = 0; k < 15; k++) feat[10 + k] = x1[(size_t)n * 15 + k];
#pragma unroll
        for (int k = 0; k < 4; k++) feat[25 + k] = sx2[k];
        float acc[15];
#pragma unroll
        for (int j = 0; j < 15; j++) acc[j] = sb1[j];
#pragma unroll
        for (int k = 0; k < 29; k++) {
            float f = feat[k];
#pragma unroll
            for (int j = 0; j < 15; j++) acc[j] += f * sw1[k * 15 + j];
        }
        v = sb2;
#pragma unroll
        for (int j = 0; j < 15; j++) { float r = (acc[j] > 0.f) ? acc[j] : 0.f; v += r * sw2[j]; }
    }
    red[threadIdx.x] = v;
    __syncthreads();
    for (int s = 128; s > 0; s >>= 1) {
        if (threadIdx.x < (unsigned)s) red[threadIdx.x] += red[threadIdx.x + s];
        __syncthreads();
    }
    if (threadIdx.x == 0) atomicAdd(&g_vsum[0], red[0]);
}

// -------- finalize (f32 output): out[0]=V, out[1..M]=log_softmax(p) --------
__global__ void k_final(float* __restrict__ out, int M, int N) {
    __shared__ float red[1024];
    int tid = threadIdx.x;
    float mx = -1e30f;
    for (int i = tid; i < M; i += 1024) mx = fmaxf(mx, g_p[i]);
    red[tid] = mx;
    __syncthreads();
    for (int s = 512; s > 0; s >>= 1) {
        if (tid < s) red[tid] = fmaxf(red[tid], red[tid + s]);
        __syncthreads();
    }
    float pmax = red[0];
    __syncthreads();
    float sm = 0.f;
    for (int i = tid; i < M; i += 1024) sm += __expf(g_p[i] - pmax);
    red[tid] = sm;
    __syncthreads();
    for (int s = 512; s > 0; s >>= 1) {
        if (tid < s) red[tid] += red[tid + s];
        __syncthreads();
    }
    float lse = pmax + logf(red[0]);
    if (tid == 0) out[0] = tanhf(g_vsum[0] / (float)N);
    for (int i = tid; i < M; i += 1024) out[1 + i] = g_p[i] - lse;
}

extern "C" void kernel_launch(void* const* d_in, const int* in_sizes, int n_in,
                              void* d_out, int out_size, void* d_ws, size_t ws_size,
                              hipStream_t stream) {
    const float* x1 = (const float*)d_in[0];
    const float* x2 = (const float*)d_in[1];
    const int* edges = (const int*)d_in[2];
    const int* asrc = (const int*)d_in[3];
    const int* adst = (const int*)d_in[4];
    const float* aarm = (const float*)d_in[5];
    const int* amove = (const int*)d_in[6];
    const int* dtar = (const int*)d_in[7];
    const float* darm = (const float*)d_in[8];
    const int* dmove = (const int*)d_in[9];
    const int pb = n_in - 24;
    const float* g1_wl  = (const float*)d_in[pb + 0];
    const float* g1_wr  = (const float*)d_in[pb + 1];
    const float* g1_att = (const float*)d_in[pb + 2];
    const float* g1_b   = (const float*)d_in[pb + 3];
    const float* g2_wl  = (const float*)d_in[pb + 4];
    const float* g2_wr  = (const float*)d_in[pb + 5];
    const float* g2_att = (const float*)d_in[pb + 6];
    const float* g2_b   = (const float*)d_in[pb + 7];
    const float* g3_wl  = (const float*)d_in[pb + 8];
    const float* g3_wr  = (const float*)d_in[pb + 9];
    const float* g3_att = (const float*)d_in[pb + 10];
    const float* g3_b   = (const float*)d_in[pb + 11];
    const float* lin_w  = (const float*)d_in[pb + 12];
    const float* lin_b  = (const float*)d_in[pb + 13];
    const float* lin2_w = (const float*)d_in[pb + 14];
    const float* lin2_b = (const float*)d_in[pb + 15];
    const float* aaa_w  = (const float*)d_in[pb + 16];
    const float* aaa_b  = (const float*)d_in[pb + 17];
    const float* bbb_w  = (const float*)d_in[pb + 18];
    const float* bbb_b  = (const float*)d_in[pb + 19];
    const float* ccc_w  = (const float*)d_in[pb + 20];
    const float* ccc_b  = (const float*)d_in[pb + 21];
    const float* ddd_w  = (const float*)d_in[pb + 22];
    const float* ddd_b  = (const float*)d_in[pb + 23];

    int N = in_sizes[0] / 15;
    int E = in_sizes[2] / 2;
    const int Ma = in_sizes[3];
    const int Md = in_sizes[7];
    int M = out_size - 1;
    if (N > N_CAP) N = N_CAP;
    if (E > E_CAP) E = E_CAP;
    if (M > M_CAP) M = M_CAP;
    const int* src = edges;
    const int* dst = edges + E;

    const int nb = (N + 255) / 256;
    const int nbk = (N + 1023) >> BKS;
    const int nsc = (E + CHUNK - 1) / CHUNK;

    // init + locality-aware CSR build (once; reused by all 3 layers)
    k_init<<<(M + 256) / 256, 256, 0, stream>>>(M);
    k_bhist<<<256, 256, 0, stream>>>(dst, E);
    k_bscan<<<1, 256, 0, stream>>>();
    k_bscatter<<<nsc, 256, 0, stream>>>(src, dst, E);
    k_bgroup<<<nbk, 256, 0, stream>>>(N, E, nbk);

    // layer 1
    k_gat_pre<<<nb, 256, 0, stream>>>(x1, g1_wl, g1_wr, 15, N);
    k_gat_gather<<<nb, 256, 0, stream>>>(g1_att, g1_b, N);
    // layer 2
    k_gat_pre<<<nb, 256, 0, stream>>>(x1, g2_wl, g2_wr, 25, N);
    k_gat_gather<<<nb, 256, 0, stream>>>(g2_att, g2_b, N);
    // layer 3
    k_gat_pre<<<nb, 256, 0, stream>>>(x1, g3_wl, g3_wr, 25, N);
    k_gat_gather<<<nb, 256, 0, stream>>>(g3_att, g3_b, N);

    // pre-project node features into score space, then score orders
    k_prep<<<nb, 256, 0, stream>>>(x1, aaa_w, ccc_w, N);
    k_attack<<<(Ma + 255) / 256, 256, 0, stream>>>(asrc, adst, aarm, amove,
                                                   aaa_w, aaa_b, bbb_w, bbb_b, Ma);
    k_deploy<<<(Md + 255) / 256, 256, 0, stream>>>(dtar, darm, dmove,
                                                   ccc_w, ccc_b, ddd_w, ddd_b, Md);
    k_value<<<nb, 256, 0, stream>>>(x1, x2, lin_w, lin_b, lin2_w, lin2_b, N);
    k_final<<<1, 1024, 0, stream>>>((float*)d_out, M, N);
}

// Round 13
// 676.519 us; speedup vs baseline: 9.8143x; 1.1677x over previous
//
#include <hip/hip_runtime.h>
#include <hip/hip_bf16.h>

#define HS 12       // stride for h / xl / xr rows (48B = 3 x float4)
#define USU 12      // stride (uints) for packed bf16 u-rows (48B = 3 x uint4)
#define N_CAP 200000
#define M_CAP 32768
#define E_CAP 3200000
#define BKS 10      // bucket shift: 1024 nodes per bucket
#define CHUNK 16384 // edges per k_bscatter block

// Static device scratch (16B-aligned rows for vector gathers)
__device__ __align__(16) float    g_h [(size_t)N_CAP * HS];
__device__ __align__(16) float    g_xl[(size_t)N_CAP * HS];
__device__ __align__(16) float    g_xr[(size_t)N_CAP * HS];
__device__ __align__(16) unsigned g_us[(size_t)N_CAP * USU];  // attack src-role (bf16x2 packed)
__device__ __align__(16) unsigned g_ud[(size_t)N_CAP * USU];  // attack dst-role (extra folded)
__device__ __align__(16) unsigned g_ut[(size_t)N_CAP * USU];  // deploy target
__device__ int      g_cnt[N_CAP];
__device__ int      g_off[N_CAP];
__device__ int      g_bcnt[256];
__device__ int      g_boff[256];
__device__ int      g_bcur[256];
__device__ unsigned g_staged[E_CAP]; // (src<<10)|local_dst, grouped by coarse bucket
__device__ int      g_csrc[E_CAP];   // CSR: src of each incoming edge, grouped by dst
__device__ float    g_p[M_CAP];
__device__ float    g_vsum[1];

__device__ __forceinline__ void load_row10(const float* row, float* v) {
    const float4* r4 = (const float4*)row;
    float4 a = r4[0], b = r4[1];
    float2 c = ((const float2*)row)[4];
    v[0] = a.x; v[1] = a.y; v[2] = a.z; v[3] = a.w;
    v[4] = b.x; v[5] = b.y; v[6] = b.z; v[7] = b.w;
    v[8] = c.x; v[9] = c.y;
}
__device__ __forceinline__ unsigned pack_bf2(float a, float b) {
    unsigned ua = __float_as_uint(a); ua = (ua + 0x7fffu + ((ua >> 16) & 1u)) >> 16;
    unsigned ub = __float_as_uint(b); ub = (ub + 0x7fffu + ((ub >> 16) & 1u)) >> 16;
    return ua | (ub << 16);
}
__device__ __forceinline__ void unpack_bf2(unsigned u, float& a, float& b) {
    a = __uint_as_float(u << 16);
    b = __uint_as_float(u & 0xffff0000u);
}
__device__ __forceinline__ void load_row20_bf(const unsigned* row, float* v) {
    const uint4* r4 = (const uint4*)row;
    uint4 q0 = r4[0], q1 = r4[1], q2 = r4[2];
    unpack_bf2(q0.x, v[0], v[1]);   unpack_bf2(q0.y, v[2], v[3]);
    unpack_bf2(q0.z, v[4], v[5]);   unpack_bf2(q0.w, v[6], v[7]);
    unpack_bf2(q1.x, v[8], v[9]);   unpack_bf2(q1.y, v[10], v[11]);
    unpack_bf2(q1.z, v[12], v[13]); unpack_bf2(q1.w, v[14], v[15]);
    unpack_bf2(q2.x, v[16], v[17]); unpack_bf2(q2.y, v[18], v[19]);
}
__device__ __forceinline__ void store_row20_bf(unsigned* row, const float* v) {
    uint4* r4 = (uint4*)row;
    r4[0] = make_uint4(pack_bf2(v[0], v[1]), pack_bf2(v[2], v[3]),
                       pack_bf2(v[4], v[5]), pack_bf2(v[6], v[7]));
    r4[1] = make_uint4(pack_bf2(v[8], v[9]), pack_bf2(v[10], v[11]),
                       pack_bf2(v[12], v[13]), pack_bf2(v[14], v[15]));
    r4[2] = make_uint4(pack_bf2(v[16], v[17]), pack_bf2(v[18], v[19]), 0u, 0u);
}

// ---------------- init: zero p, vsum, bucket counts ----------------
__global__ void k_init(int M) {
    int i = blockIdx.x * blockDim.x + threadIdx.x;
    if (i < M) g_p[i] = 0.f;
    if (i < 256) g_bcnt[i] = 0;
    if (i == M) g_vsum[0] = 0.f;
}

// ---------------- coarse bucket histogram (LDS-aggregated) ----------------
__global__ void k_bhist(const int* __restrict__ dst, int E) {
    __shared__ int hist[256];
    hist[threadIdx.x] = 0;
    __syncthreads();
    for (int e = blockIdx.x * blockDim.x + threadIdx.x; e < E; e += gridDim.x * blockDim.x)
        atomicAdd(&hist[dst[e] >> BKS], 1);
    __syncthreads();
    int v = hist[threadIdx.x];
    if (v) atomicAdd(&g_bcnt[threadIdx.x], v);
}

// ---------------- scan of 256 bucket counts (one block) ----------------
__global__ void k_bscan() {
    __shared__ int s[256];
    int t = threadIdx.x;
    int v = g_bcnt[t];
    s[t] = v;
    __syncthreads();
    for (int d = 1; d < 256; d <<= 1) {
        int x = (t >= d) ? s[t - d] : 0;
        __syncthreads();
        s[t] += x;
        __syncthreads();
    }
    g_boff[t] = s[t] - v;
    g_bcur[t] = s[t] - v;
}

// ---------------- bucket scatter: packed (src,local_dst) -> staged ----------------
__global__ void k_bscatter(const int* __restrict__ src, const int* __restrict__ dst, int E) {
    __shared__ int hist[256], cur[256];
    int lo = blockIdx.x * CHUNK;
    int hi = lo + CHUNK; if (hi > E) hi = E;
    int tid = threadIdx.x;
    hist[tid] = 0;
    __syncthreads();
    for (int e = lo + tid; e < hi; e += 256) atomicAdd(&hist[dst[e] >> BKS], 1);
    __syncthreads();
    cur[tid] = atomicAdd(&g_bcur[tid], hist[tid]);   // reserve contiguous ranges
    __syncthreads();
    for (int e = lo + tid; e < hi; e += 256) {
        int d = dst[e];
        int pos = atomicAdd(&cur[d >> BKS], 1);
        g_staged[pos] = ((unsigned)src[e] << BKS) | (unsigned)(d & ((1 << BKS) - 1));
    }
}

// ------- per-bucket exact grouping: builds g_off/g_cnt/g_csrc (one block/bucket) -------
__global__ void k_bgroup(int N, int E, int nbk) {
    __shared__ int cnt[1024], offl[1024], ssum[256];
    int b = blockIdx.x;
    int nodebase = b << BKS;
    int nnodes = N - nodebase; if (nnodes > 1024) nnodes = 1024;
    int bstart = g_boff[b];
    int bend = (b + 1 < nbk) ? g_boff[b + 1] : E;
    int tid = threadIdx.x;
    for (int j = tid; j < 1024; j += 256) cnt[j] = 0;
    __syncthreads();
    for (int e = bstart + tid; e < bend; e += 256)
        atomicAdd(&cnt[g_staged[e] & 1023u], 1);
    __syncthreads();
    int s0 = cnt[4 * tid], s1 = cnt[4 * tid + 1], s2 = cnt[4 * tid + 2], s3 = cnt[4 * tid + 3];
    int tsum = s0 + s1 + s2 + s3;
    ssum[tid] = tsum;
    __syncthreads();
    for (int d = 1; d < 256; d <<= 1) {
        int x = (tid >= d) ? ssum[tid - d] : 0;
        __syncthreads();
        ssum[tid] += x;
        __syncthreads();
    }
    int base = ssum[tid] - tsum;
    offl[4 * tid] = base;
    offl[4 * tid + 1] = base + s0;
    offl[4 * tid + 2] = base + s0 + s1;
    offl[4 * tid + 3] = base + s0 + s1 + s2;
    __syncthreads();
    for (int j = tid; j < nnodes; j += 256) {
        g_off[nodebase + j] = bstart + offl[j];
        g_cnt[nodebase + j] = cnt[j];
    }
    __syncthreads();
    for (int j = tid; j < 1024; j += 256) cnt[j] = offl[j];  // repurpose as cursors
    __syncthreads();
    for (int e = bstart + tid; e < bend; e += 256) {
        unsigned v = g_staged[e];
        int p = atomicAdd(&cnt[v & 1023u], 1);
        g_csrc[bstart + p] = (int)(v >> BKS);
    }
}

// ---- per-node xl/xr from [hprev|x1] (reads g_h of prev layer when in_dim==25) ----
__global__ void k_gat_pre(const float* __restrict__ x1,
                          const float* __restrict__ wl, const float* __restrict__ wr,
                          int in_dim, int N) {
    __shared__ float swl[250], swr[250];
    for (int t = threadIdx.x; t < in_dim * 10; t += blockDim.x) { swl[t] = wl[t]; swr[t] = wr[t]; }
    __syncthreads();
    int n = blockIdx.x * blockDim.x + threadIdx.x;
    if (n >= N) return;
    float aL[10], aR[10];
#pragma unroll
    for (int j = 0; j < 10; j++) { aL[j] = 0.f; aR[j] = 0.f; }
    int row = 0;
    if (in_dim == 25) {
        float hv[10];
        load_row10(&g_h[(size_t)n * HS], hv);
        for (int k = 0; k < 10; k++) {
            float v = hv[k];
#pragma unroll
            for (int j = 0; j < 10; j++) { aL[j] += v * swl[k * 10 + j]; aR[j] += v * swr[k * 10 + j]; }
        }
        row = 10;
    }
    for (int k = 0; k < 15; k++) {
        float v = x1[(size_t)n * 15 + k];
#pragma unroll
        for (int j = 0; j < 10; j++) { aL[j] += v * swl[(row + k) * 10 + j]; aR[j] += v * swr[(row + k) * 10 + j]; }
    }
#pragma unroll
    for (int j = 0; j < 10; j++) { g_xl[(size_t)n * HS + j] = aL[j]; g_xr[(size_t)n * HS + j] = aR[j]; }
}

// ---- gather, 4 lanes per node: online softmax + shfl_xor state merge ----
__global__ void k_gat_gather(const float* __restrict__ att, const float* __restrict__ b, int N) {
    __shared__ float satt[10], sb[10];
    if (threadIdx.x < 10) { satt[threadIdx.x] = att[threadIdx.x]; sb[threadIdx.x] = b[threadIdx.x]; }
    __syncthreads();
    int t = blockIdx.x * blockDim.x + threadIdx.x;
    int n = t >> 2, sub = t & 3;
    if (n >= N) return;
    float xr[10];
    load_row10(&g_xr[(size_t)n * HS], xr);
    float m = -1e30f, den = 0.f, num[10];
#pragma unroll
    for (int j = 0; j < 10; j++) num[j] = 0.f;
    if (sub == 0) {   // self-loop handled by lane 0
        float xls[10];
        load_row10(&g_xl[(size_t)n * HS], xls);
        float acc = 0.f;
#pragma unroll
        for (int k = 0; k < 10; k++) {
            float v = xls[k] + xr[k];
            v = (v > 0.f) ? v : 0.2f * v;
            acc += v * satt[k];
            num[k] = xls[k];
        }
        m = acc;
        den = 1.f;
    }
    int lo = g_off[n], hi = lo + g_cnt[n];
    for (int e = lo + sub; e < hi; e += 4) {
        int s = g_csrc[e];
        float xls[10];
        load_row10(&g_xl[(size_t)s * HS], xls);
        float acc = 0.f;
#pragma unroll
        for (int k = 0; k < 10; k++) {
            float v = xls[k] + xr[k];
            v = (v > 0.f) ? v : 0.2f * v;
            acc += v * satt[k];
        }
        if (acc > m) {
            float sc = __expf(m - acc);
            den *= sc;
#pragma unroll
            for (int j = 0; j < 10; j++) num[j] *= sc;
            m = acc;
        }
        float w = __expf(acc - m);
        den += w;
#pragma unroll
        for (int j = 0; j < 10; j++) num[j] += w * xls[j];
    }
    // merge the 4 lane-partial softmax states
#pragma unroll
    for (int off = 1; off <= 2; off <<= 1) {
        float m2 = __shfl_xor(m, off);
        float d2 = __shfl_xor(den, off);
        float M = fmaxf(m, m2);
        float s1 = __expf(m - M), s2 = __expf(m2 - M);
        den = den * s1 + d2 * s2;
#pragma unroll
        for (int j = 0; j < 10; j++) {
            float n2 = __shfl_xor(num[j], off);
            num[j] = num[j] * s1 + n2 * s2;
        }
        m = M;
    }
    if (sub == 0) {
        float inv = 1.f / den;
#pragma unroll
        for (int j = 0; j < 10; j++) {
            float v = num[j] * inv + sb[j];
            g_h[(size_t)n * HS + j] = (v > 0.f) ? v : 0.f;
        }
    }
}

// ---- pre-project per-node features into score space (bf16-packed outputs) ----
__global__ void k_prep(const float* __restrict__ x1,
                       const float* __restrict__ aw, const float* __restrict__ cw, int N) {
    __shared__ float sA[48 * 20], sC[23 * 20];
    for (int t = threadIdx.x; t < 48 * 20; t += blockDim.x) sA[t] = aw[t];
    for (int t = threadIdx.x; t < 23 * 20; t += blockDim.x) sC[t] = cw[t];
    __syncthreads();
    int n = blockIdx.x * blockDim.x + threadIdx.x;
    if (n >= N) return;
    float hv[10], xv[15];
    load_row10(&g_h[(size_t)n * HS], hv);
#pragma unroll
    for (int k = 0; k < 15; k++) xv[k] = x1[(size_t)n * 15 + k];
    float us[20], ud[20], ut[20];
#pragma unroll
    for (int j = 0; j < 20; j++) { us[j] = 0.f; ud[j] = 0.f; ut[j] = 0.f; }
    for (int k = 0; k < 10; k++) {
        float h = hv[k];
#pragma unroll
        for (int j = 0; j < 20; j++) {
            us[j] += h * sA[k * 20 + j];
            ud[j] += h * sA[(10 + k) * 20 + j];
            ut[j] += h * sC[k * 20 + j];
        }
    }
    for (int k = 0; k < 12; k++) {
        float v = xv[3 + k];
#pragma unroll
        for (int j = 0; j < 20; j++) {
            us[j] += v * sA[(20 + k) * 20 + j];
            ut[j] += v * sC[(10 + k) * 20 + j];
        }
    }
    for (int k = 0; k < 14; k++) {
        float v = xv[1 + k];
#pragma unroll
        for (int j = 0; j < 20; j++) ud[j] += v * sA[(32 + k) * 20 + j];
    }
    float t34 = -0.7f * (xv[3] + xv[4]);
#pragma unroll
    for (int j = 0; j < 20; j++) ud[j] += t34 * sA[47 * 20 + j];
    store_row20_bf(&g_us[(size_t)n * USU], us);
    store_row20_bf(&g_ud[(size_t)n * USU], ud);
    store_row20_bf(&g_ut[(size_t)n * USU], ut);
}

// ---------------- attack order scoring (pre-projected, bf16 rows) ----------------
__global__ void k_attack(const int* __restrict__ asrc, const int* __restrict__ adst,
                         const float* __restrict__ aarm, const int* __restrict__ amove,
                         const float* __restrict__ aw, const float* __restrict__ ab,
                         const float* __restrict__ bw, const float* __restrict__ bb,
                         int Ma) {
    __shared__ float swa[20], sab[20], sw2[20], sb2;
    if (threadIdx.x < 20) {
        swa[threadIdx.x] = aw[46 * 20 + threadIdx.x] + 0.6f * aw[47 * 20 + threadIdx.x];
        sab[threadIdx.x] = ab[threadIdx.x];
        sw2[threadIdx.x] = bw[threadIdx.x];
    }
    if (threadIdx.x == 0) sb2 = bb[0];
    __syncthreads();
    int i = blockIdx.x * blockDim.x + threadIdx.x;
    if (i >= Ma) return;
    int s = asrc[i], d = adst[i];
    float a = aarm[i];
    float us[20], ud[20];
    load_row20_bf(&g_us[(size_t)s * USU], us);
    load_row20_bf(&g_ud[(size_t)d * USU], ud);
    float sres = sb2;
#pragma unroll
    for (int j = 0; j < 20; j++) {
        float acc = sab[j] + us[j] + ud[j] + a * swa[j];
        float r = (acc > 0.f) ? acc : 0.f;
        sres += r * sw2[j];
    }
    atomicAdd(&g_p[amove[i]], sres);
}

// ---------------- deploy order scoring (pre-projected, bf16 rows) ----------------
__global__ void k_deploy(const int* __restrict__ dtar, const float* __restrict__ darm,
                         const int* __restrict__ dmove,
                         const float* __restrict__ cw, const float* __restrict__ cb,
                         const float* __restrict__ dw, const float* __restrict__ db,
                         int Md) {
    __shared__ float swa[20], scb[20], sw2[20], sb2;
    if (threadIdx.x < 20) {
        swa[threadIdx.x] = cw[22 * 20 + threadIdx.x];
        scb[threadIdx.x] = cb[threadIdx.x];
        sw2[threadIdx.x] = dw[threadIdx.x];
    }
    if (threadIdx.x == 0) sb2 = db[0];
    __syncthreads();
    int i = blockIdx.x * blockDim.x + threadIdx.x;
    if (i >= Md) return;
    int t = dtar[i];
    float a = darm[i];
    float ut[20];
    load_row20_bf(&g_ut[(size_t)t * USU], ut);
    float sres = sb2;
#pragma unroll
    for (int j = 0; j < 20; j++) {
        float acc = scb[j] + ut[j] + a * swa[j];
        float r = (acc > 0.f) ? acc : 0.f;
        sres += r * sw2[j];
    }
    atomicAdd(&g_p[dmove[i]], sres);
}

// ---------------- value head ----------------
__global__ void k_value(const float* __restrict__ x1, const float* __restrict__ x2,
                        const float* __restrict__ w1, const float* __restrict__ b1,
                        const float* __restrict__ w2, const float* __restrict__ bias2, int N) {
    __shared__ float sw1[29 * 15], sb1[15], sw2[15], sx2[4], sb2;
    __shared__ float red[256];
    for (int t = threadIdx.x; t < 29 * 15; t += blockDim.x) sw1[t] = w1[t];
    if (threadIdx.x < 15) { sb1[threadIdx.x] = b1[threadIdx.x]; sw2[threadIdx.x] = w2[threadIdx.x]; }
    if (threadIdx.x < 4) sx2[threadIdx.x] = x2[threadIdx.x];
    if (threadIdx.x == 0) sb2 = bias2[0];
    __syncthreads();
    int n = blockIdx.x * blockDim.x + threadIdx.x;
    float v = 0.f;
    if (n < N) {
        float feat[29];
        load_row10(&g_h[(size_t)n * HS], feat);
#pragma unroll
        for (int k = 0; k < 15; k++) feat[10 + k] = x1[(size_t)n * 15 + k];
#pragma unroll
        for (int k = 0; k < 4; k++) feat[25 + k] = sx2[k];
        float acc[15];
#pragma unroll
        for (int j = 0; j < 15; j++) acc[j] = sb1[j];
#pragma unroll
        for (int k = 0; k < 29; k++) {
            float f = feat[k];
#pragma unroll
            for (int j = 0; j < 15; j++) acc[j] += f * sw1[k * 15 + j];
        }
        v = sb2;
#pragma unroll
        for (int j = 0; j < 15; j++) { float r = (acc[j] > 0.f) ? acc[j] : 0.f; v += r * sw2[j]; }
    }
    red[threadIdx.x] = v;
    __syncthreads();
    for (int s = 128; s > 0; s >>= 1) {
        if (threadIdx.x < (unsigned)s) red[threadIdx.x] += red[threadIdx.x + s];
        __syncthreads();
    }
    if (threadIdx.x == 0) atomicAdd(&g_vsum[0], red[0]);
}

// -------- finalize (f32 output): out[0]=V, out[1..M]=log_softmax(p) --------
__global__ void k_final(float* __restrict__ out, int M, int N) {
    __shared__ float red[1024];
    int tid = threadIdx.x;
    float mx = -1e30f;
    for (int i = tid; i < M; i += 1024) mx = fmaxf(mx, g_p[i]);
    red[tid] = mx;
    __syncthreads();
    for (int s = 512; s > 0; s >>= 1) {
        if (tid < s) red[tid] = fmaxf(red[tid], red[tid + s]);
        __syncthreads();
    }
    float pmax = red[0];
    __syncthreads();
    float sm = 0.f;
    for (int i = tid; i < M; i += 1024) sm += __expf(g_p[i] - pmax);
    red[tid] = sm;
    __syncthreads();
    for (int s = 512; s > 0; s >>= 1) {
        if (tid < s) red[tid] += red[tid + s];
        __syncthreads();
    }
    float lse = pmax + logf(red[0]);
    if (tid == 0) out[0] = tanhf(g_vsum[0] / (float)N);
    for (int i = tid; i < M; i += 1024) out[1 + i] = g_p[i] - lse;
}

extern "C" void kernel_launch(void* const* d_in, const int* in_sizes, int n_in,
                              void* d_out, int out_size, void* d_ws, size_t ws_size,
                              hipStream_t stream) {
    const float* x1 = (const float*)d_in[0];
    const float* x2 = (const float*)d_in[1];
    const int* edges = (const int*)d_in[2];
    const int* asrc = (const int*)d_in[3];
    const int* adst = (const int*)d_in[4];
    const float* aarm = (const float*)d_in[5];
    const int* amove = (const int*)d_in[6];
    const int* dtar = (const int*)d_in[7];
    const float* darm = (const float*)d_in[8];
    const int* dmove = (const int*)d_in[9];
    const int pb = n_in - 24;
    const float* g1_wl  = (const float*)d_in[pb + 0];
    const float* g1_wr  = (const float*)d_in[pb + 1];
    const float* g1_att = (const float*)d_in[pb + 2];
    const float* g1_b   = (const float*)d_in[pb + 3];
    const float* g2_wl  = (const float*)d_in[pb + 4];
    const float* g2_wr  = (const float*)d_in[pb + 5];
    const float* g2_att = (const float*)d_in[pb + 6];
    const float* g2_b   = (const float*)d_in[pb + 7];
    const float* g3_wl  = (const float*)d_in[pb + 8];
    const float* g3_wr  = (const float*)d_in[pb + 9];
    const float* g3_att = (const float*)d_in[pb + 10];
    const float* g3_b   = (const float*)d_in[pb + 11];
    const float* lin_w  = (const float*)d_in[pb + 12];
    const float* lin_b  = (const float*)d_in[pb + 13];
    const float* lin2_w = (const float*)d_in[pb + 14];
    const float* lin2_b = (const float*)d_in[pb + 15];
    const float* aaa_w  = (const float*)d_in[pb + 16];
    const float* aaa_b  = (const float*)d_in[pb + 17];
    const float* bbb_w  = (const float*)d_in[pb + 18];
    const float* bbb_b  = (const float*)d_in[pb + 19];
    const float* ccc_w  = (const float*)d_in[pb + 20];
    const float* ccc_b  = (const float*)d_in[pb + 21];
    const float* ddd_w  = (const float*)d_in[pb + 22];
    const float* ddd_b  = (const float*)d_in[pb + 23];

    int N = in_sizes[0] / 15;
    int E = in_sizes[2] / 2;
    const int Ma = in_sizes[3];
    const int Md = in_sizes[7];
    int M = out_size - 1;
    if (N > N_CAP) N = N_CAP;
    if (E > E_CAP) E = E_CAP;
    if (M > M_CAP) M = M_CAP;
    const int* src = edges;
    const int* dst = edges + E;

    const int nb = (N + 255) / 256;
    const int nb4 = (4 * N + 255) / 256;
    const int nbk = (N + 1023) >> BKS;
    const int nsc = (E + CHUNK - 1) / CHUNK;

    // init + locality-aware CSR build (once; reused by all 3 layers)
    k_init<<<(M + 256) / 256, 256, 0, stream>>>(M);
    k_bhist<<<256, 256, 0, stream>>>(dst, E);
    k_bscan<<<1, 256, 0, stream>>>();
    k_bscatter<<<nsc, 256, 0, stream>>>(src, dst, E);
    k_bgroup<<<nbk, 256, 0, stream>>>(N, E, nbk);

    // layer 1
    k_gat_pre<<<nb, 256, 0, stream>>>(x1, g1_wl, g1_wr, 15, N);
    k_gat_gather<<<nb4, 256, 0, stream>>>(g1_att, g1_b, N);
    // layer 2
    k_gat_pre<<<nb, 256, 0, stream>>>(x1, g2_wl, g2_wr, 25, N);
    k_gat_gather<<<nb4, 256, 0, stream>>>(g2_att, g2_b, N);
    // layer 3
    k_gat_pre<<<nb, 256, 0, stream>>>(x1, g3_wl, g3_wr, 25, N);
    k_gat_gather<<<nb4, 256, 0, stream>>>(g3_att, g3_b, N);

    // pre-project node features into score space, then score orders
    k_prep<<<nb, 256, 0, stream>>>(x1, aaa_w, ccc_w, N);
    k_attack<<<(Ma + 255) / 256, 256, 0, stream>>>(asrc, adst, aarm, amove,
                                                   aaa_w, aaa_b, bbb_w, bbb_b, Ma);
    k_deploy<<<(Md + 255) / 256, 256, 0, stream>>>(dtar, darm, dmove,
                                                   ccc_w, ccc_b, ddd_w, ddd_b, Md);
    k_value<<<nb, 256, 0, stream>>>(x1, x2, lin_w, lin_b, lin2_w, lin2_b, N);
    k_final<<<1, 1024, 0, stream>>>((float*)d_out, M, N);
}